// Round 1
// baseline (529.888 us; speedup 1.0000x reference)
//
#include <hip/hip_runtime.h>
#include <hip/hip_bf16.h>

#define BTOT 4
#define NPTS 4096
#define FTOT 6
#define KNN 8
#define EPSV 1e-3f

// ---------------- bn1: x = (in - mean) * rsqrt(var+eps) * gamma + beta ----------------
__global__ __launch_bounds__(256) void k_bn1(const float* __restrict__ in,
                                             const float* __restrict__ g,
                                             const float* __restrict__ b,
                                             const float* __restrict__ m,
                                             const float* __restrict__ v,
                                             float* __restrict__ x) {
    int i = blockIdx.x * 256 + threadIdx.x;
    if (i >= BTOT * NPTS) return;
#pragma unroll
    for (int f = 0; f < FTOT; ++f) {
        float val = in[(size_t)i * FTOT + f];
        x[(size_t)i * FTOT + f] = (val - m[f]) * rsqrtf(v[f] + EPSV) * g[f] + b[f];
    }
}

// ---------------- KNN: top-9 smallest d2 (ties -> smaller index), drop head ----------------
__global__ __launch_bounds__(256) void k_knn(const float* __restrict__ x,
                                             int* __restrict__ idx) {
    __shared__ float2 spos[NPTS];  // 32 KB
    int b = blockIdx.x >> 4;                       // 16 blocks per batch
    int qi = (blockIdx.x & 15) * 256 + threadIdx.x;
    const float* xb = x + (size_t)b * NPTS * FTOT;
    for (int j = threadIdx.x; j < NPTS; j += 256)
        spos[j] = make_float2(xb[(size_t)j * FTOT], xb[(size_t)j * FTOT + 1]);
    __syncthreads();

    float2 q = spos[qi];
    float bd[9];
    int   bi[9];
#pragma unroll
    for (int m = 0; m < 9; ++m) { bd[m] = 3.4e38f; bi[m] = -1; }

    for (int j = 0; j < NPTS; ++j) {
        float2 p = spos[j];
        float dx = q.x - p.x;
        float dy = q.y - p.y;
        // forbid FMA contraction: must match plain fp32 mul/mul/add rounding
        float d2 = __fadd_rn(__fmul_rn(dx, dx), __fmul_rn(dy, dy));
        if (d2 < bd[8]) {
            bd[8] = d2; bi[8] = j;
#pragma unroll
            for (int m = 8; m > 0; --m) {
                if (bd[m] < bd[m - 1]) {   // strict: equal keeps earlier (smaller) index first
                    float td = bd[m]; bd[m] = bd[m - 1]; bd[m - 1] = td;
                    int   ti = bi[m]; bi[m] = bi[m - 1]; bi[m - 1] = ti;
                }
            }
        }
    }
#pragma unroll
    for (int k = 0; k < KNN; ++k)
        idx[((size_t)b * NPTS + qi) * KNN + k] = bi[k + 1];  // drop nearest (self)
}

// ---------------- gravnet1: gather 4-feat, mean, 4->32 relu -> 32; write xcat[0:34) ----------------
__global__ __launch_bounds__(256) void k_g1(const float* __restrict__ x,
                                            const int* __restrict__ idx,
                                            const float* __restrict__ w1,
                                            const float* __restrict__ b1,
                                            const float* __restrict__ w2,
                                            const float* __restrict__ b2,
                                            float* __restrict__ xcat) {
    __shared__ float sw1[4 * 32], sw2[32 * 32], sb1[32], sb2[32];
    int t = threadIdx.x;
    if (t < 128) sw1[t] = w1[t];
    for (int u = t; u < 1024; u += 256) sw2[u] = w2[u];
    if (t < 32) { sb1[t] = b1[t]; sb2[t] = b2[t]; }
    __syncthreads();

    int i = blockIdx.x * 256 + t;
    int b = i >> 12;
    int n = i & (NPTS - 1);
    const float* xb = x + (size_t)b * NPTS * FTOT;

    float agg[4] = {0.f, 0.f, 0.f, 0.f};
#pragma unroll
    for (int k = 0; k < KNN; ++k) {
        int nb = idx[(size_t)i * KNN + k];
        const float* f = xb + (size_t)nb * FTOT + 2;
        agg[0] += f[0]; agg[1] += f[1]; agg[2] += f[2]; agg[3] += f[3];
    }
#pragma unroll
    for (int k = 0; k < 4; ++k) agg[k] *= 0.125f;

    float h[32];
#pragma unroll
    for (int o = 0; o < 32; ++o) {
        float a = sb1[o];
#pragma unroll
        for (int k = 0; k < 4; ++k) a += agg[k] * sw1[k * 32 + o];
        h[o] = fmaxf(a, 0.f);
    }
    float* oc = xcat + (size_t)i * 68;
    oc[0] = xb[(size_t)n * FTOT];
    oc[1] = xb[(size_t)n * FTOT + 1];
#pragma unroll
    for (int o = 0; o < 32; ++o) {
        float a = sb2[o];
#pragma unroll
        for (int k = 0; k < 32; ++k) a += h[k] * sw2[k * 32 + o];
        oc[2 + o] = a;
    }
}

// ---------------- gravnet2: gather 32-feat (xcat cols 2..33), mean, 32->32 relu -> 32; write xcat[34:68) ----------------
__global__ __launch_bounds__(256) void k_g2(float* __restrict__ xcat,
                                            const int* __restrict__ idx,
                                            const float* __restrict__ w1,
                                            const float* __restrict__ b1,
                                            const float* __restrict__ w2,
                                            const float* __restrict__ b2) {
    __shared__ float sw1[32 * 32], sw2[32 * 32], sb1[32], sb2[32];
    int t = threadIdx.x;
    for (int u = t; u < 1024; u += 256) { sw1[u] = w1[u]; sw2[u] = w2[u]; }
    if (t < 32) { sb1[t] = b1[t]; sb2[t] = b2[t]; }
    __syncthreads();

    int i = blockIdx.x * 256 + t;
    int b = i >> 12;

    float agg[32];
#pragma unroll
    for (int j = 0; j < 32; ++j) agg[j] = 0.f;
#pragma unroll
    for (int k = 0; k < KNN; ++k) {
        int nb = idx[(size_t)i * KNN + k];
        const float* f = xcat + ((size_t)b * NPTS + nb) * 68 + 2;
#pragma unroll
        for (int j = 0; j < 32; ++j) agg[j] += f[j];
    }
#pragma unroll
    for (int j = 0; j < 32; ++j) agg[j] *= 0.125f;

    float h[32];
#pragma unroll
    for (int o = 0; o < 32; ++o) {
        float a = sb1[o];
#pragma unroll
        for (int k = 0; k < 32; ++k) a += agg[k] * sw1[k * 32 + o];
        h[o] = fmaxf(a, 0.f);
    }
    float* oc = xcat + (size_t)i * 68;
    oc[34] = oc[0];
    oc[35] = oc[1];
#pragma unroll
    for (int o = 0; o < 32; ++o) {
        float a = sb2[o];
#pragma unroll
        for (int k = 0; k < 32; ++k) a += h[k] * sw2[k * 32 + o];
        oc[36 + o] = a;
    }
}

// ---------------- d1: (BN,68) @ (68,128) + b, relu. block = 2 points x 128 outs ----------------
__global__ __launch_bounds__(256) void k_d1(const float* __restrict__ xcat,
                                            const float* __restrict__ w,
                                            const float* __restrict__ bias,
                                            float* __restrict__ h1) {
    __shared__ float sx[2][68];
    int t = threadIdx.x;
    int p0 = blockIdx.x * 2;
    if (t < 136) sx[t / 68][t % 68] = xcat[(size_t)p0 * 68 + t];
    __syncthreads();
    int pl = t >> 7, o = t & 127;
    float a = bias[o];
#pragma unroll 4
    for (int k = 0; k < 68; ++k) a += sx[pl][k] * w[k * 128 + o];
    h1[(size_t)(p0 + pl) * 128 + o] = fmaxf(a, 0.f);
}

// ---------------- d2: (BN,128) @ (128,64) + b, relu. block = 4 points x 64 outs ----------------
__global__ __launch_bounds__(256) void k_d2(const float* __restrict__ h1,
                                            const float* __restrict__ w,
                                            const float* __restrict__ bias,
                                            float* __restrict__ h2) {
    __shared__ float sx[4][128];
    int t = threadIdx.x;
    int p0 = blockIdx.x * 4;
    for (int u = t; u < 512; u += 256) sx[u >> 7][u & 127] = h1[(size_t)p0 * 128 + u];
    __syncthreads();
    int pl = t >> 6, o = t & 63;
    float a = bias[o];
#pragma unroll 4
    for (int k = 0; k < 128; ++k) a += sx[pl][k] * w[k * 64 + o];
    h2[(size_t)(p0 + pl) * 64 + o] = fmaxf(a, 0.f);
}

// ---------------- d3: (BN,64) @ (64,32) + b, relu. block = 8 points x 32 outs ----------------
__global__ __launch_bounds__(256) void k_d3(const float* __restrict__ h2,
                                            const float* __restrict__ w,
                                            const float* __restrict__ bias,
                                            float* __restrict__ h3) {
    __shared__ float sx[8][64];
    int t = threadIdx.x;
    int p0 = blockIdx.x * 8;
    for (int u = t; u < 512; u += 256) sx[u >> 6][u & 63] = h2[(size_t)p0 * 64 + u];
    __syncthreads();
    int pl = t >> 5, o = t & 31;
    float a = bias[o];
#pragma unroll 4
    for (int k = 0; k < 64; ++k) a += sx[pl][k] * w[k * 32 + o];
    h3[(size_t)(p0 + pl) * 32 + o] = fmaxf(a, 0.f);
}

// ---------------- bn2 + out: per-point dot over 32 ----------------
__global__ __launch_bounds__(256) void k_out(const float* __restrict__ h3,
                                             const float* __restrict__ g,
                                             const float* __restrict__ be,
                                             const float* __restrict__ m,
                                             const float* __restrict__ v,
                                             const float* __restrict__ ow,
                                             const float* __restrict__ ob,
                                             float* __restrict__ out) {
    int i = blockIdx.x * 256 + threadIdx.x;
    if (i >= BTOT * NPTS) return;
    float a = ob[0];
#pragma unroll
    for (int k = 0; k < 32; ++k) {
        float val = (h3[(size_t)i * 32 + k] - m[k]) * rsqrtf(v[k] + EPSV) * g[k] + be[k];
        a += val * ow[k];
    }
    out[i] = a;
}

extern "C" void kernel_launch(void* const* d_in, const int* in_sizes, int n_in,
                              void* d_out, int out_size, void* d_ws, size_t ws_size,
                              hipStream_t stream) {
    const float* inputs    = (const float*)d_in[0];
    const float* bn1_gamma = (const float*)d_in[1];
    const float* bn1_beta  = (const float*)d_in[2];
    const float* bn1_mean  = (const float*)d_in[3];
    const float* bn1_var   = (const float*)d_in[4];
    const float* g1_w1 = (const float*)d_in[5];
    const float* g1_b1 = (const float*)d_in[6];
    const float* g1_w2 = (const float*)d_in[7];
    const float* g1_b2 = (const float*)d_in[8];
    const float* g2_w1 = (const float*)d_in[9];
    const float* g2_b1 = (const float*)d_in[10];
    const float* g2_w2 = (const float*)d_in[11];
    const float* g2_b2 = (const float*)d_in[12];
    const float* d1_w = (const float*)d_in[13];
    const float* d1_b = (const float*)d_in[14];
    const float* d2_w = (const float*)d_in[15];
    const float* d2_b = (const float*)d_in[16];
    const float* d3_w = (const float*)d_in[17];
    const float* d3_b = (const float*)d_in[18];
    const float* bn2_gamma = (const float*)d_in[19];
    const float* bn2_beta  = (const float*)d_in[20];
    const float* bn2_mean  = (const float*)d_in[21];
    const float* bn2_var   = (const float*)d_in[22];
    const float* out_w = (const float*)d_in[23];
    const float* out_b = (const float*)d_in[24];
    float* out = (float*)d_out;

    const size_t BN = (size_t)BTOT * NPTS;
    char* ws = (char*)d_ws;
    size_t off = 0;
    auto alloc = [&](size_t bytes) { char* p = ws + off; off += (bytes + 255) & ~(size_t)255; return p; };
    float* x    = (float*)alloc(BN * FTOT * sizeof(float));   // bn1 output
    int*   idx  = (int*)  alloc(BN * KNN  * sizeof(int));     // knn indices (shared by g1,g2)
    float* xcat = (float*)alloc(BN * 68   * sizeof(float));   // [x1 | x2]
    float* h1   = (float*)alloc(BN * 128  * sizeof(float));
    float* h2   = (float*)alloc(BN * 64   * sizeof(float));
    float* h3   = (float*)alloc(BN * 32   * sizeof(float));
    (void)ws_size; (void)n_in; (void)in_sizes; (void)out_size;

    dim3 blk(256);
    k_bn1<<<dim3(64), blk, 0, stream>>>(inputs, bn1_gamma, bn1_beta, bn1_mean, bn1_var, x);
    k_knn<<<dim3(64), blk, 0, stream>>>(x, idx);
    k_g1 <<<dim3(64), blk, 0, stream>>>(x, idx, g1_w1, g1_b1, g1_w2, g1_b2, xcat);
    k_g2 <<<dim3(64), blk, 0, stream>>>(xcat, idx, g2_w1, g2_b1, g2_w2, g2_b2);
    k_d1 <<<dim3(8192), blk, 0, stream>>>(xcat, d1_w, d1_b, h1);
    k_d2 <<<dim3(4096), blk, 0, stream>>>(h1, d2_w, d2_b, h2);
    k_d3 <<<dim3(2048), blk, 0, stream>>>(h2, d3_w, d3_b, h3);
    k_out<<<dim3(64), blk, 0, stream>>>(h3, bn2_gamma, bn2_beta, bn2_mean, bn2_var, out_w, out_b, out);
}

// Round 2
// 335.014 us; speedup vs baseline: 1.5817x; 1.5817x over previous
//
#include <hip/hip_runtime.h>
#include <hip/hip_bf16.h>

#define BTOT 4
#define NPTS 4096
#define FTOT 6
#define KNN 8
#define EPSV 1e-3f

__device__ __forceinline__ unsigned long long shfl_xor_u64(unsigned long long v, int mask) {
    unsigned lo = (unsigned)v, hi = (unsigned)(v >> 32);
    lo = (unsigned)__shfl_xor((int)lo, mask);
    hi = (unsigned)__shfl_xor((int)hi, mask);
    return ((unsigned long long)hi << 32) | lo;
}

// ---------------- bn1: x = (in - mean) * rsqrt(var+eps) * gamma + beta; also emit packed pos ----------------
__global__ __launch_bounds__(256) void k_bn1(const float* __restrict__ in,
                                             const float* __restrict__ g,
                                             const float* __restrict__ b,
                                             const float* __restrict__ m,
                                             const float* __restrict__ v,
                                             float* __restrict__ x,
                                             float2* __restrict__ pos) {
    int i = blockIdx.x * 256 + threadIdx.x;
    if (i >= BTOT * NPTS) return;
    float o[FTOT];
#pragma unroll
    for (int f = 0; f < FTOT; ++f) {
        float val = in[(size_t)i * FTOT + f];
        o[f] = (val - m[f]) * rsqrtf(v[f] + EPSV) * g[f] + b[f];
        x[(size_t)i * FTOT + f] = o[f];
    }
    pos[i] = make_float2(o[0], o[1]);
}

// ---------------- KNN: 16 lanes per query; exact (d2, idx) ordering via u64 keys ----------------
__global__ __launch_bounds__(256) void k_knn(const float2* __restrict__ posg,
                                             int* __restrict__ idx) {
    __shared__ float2 spos[NPTS];  // 32 KB
    int b = blockIdx.x >> 8;                   // 256 blocks per batch
    int q0 = (blockIdx.x & 255) << 4;          // 16 queries per block
    int t = threadIdx.x;
    const float2* pb = posg + (size_t)b * NPTS;
    for (int j = t; j < NPTS; j += 256) spos[j] = pb[j];
    __syncthreads();

    int lq = t >> 4;          // local query 0..15
    int p  = t & 15;          // partition lane 0..15
    int qq = q0 + lq;
    float2 q = spos[qq];

    unsigned long long K[9];
#pragma unroll
    for (int m = 0; m < 9; ++m) K[m] = ~0ULL;

    // strided partition: lane p scans j = jj*16 + p  (ascending j within lane)
    for (int jj = 0; jj < NPTS / 16; ++jj) {
        int j = (jj << 4) + p;
        float2 pt = spos[j];
        float dx = q.x - pt.x;
        float dy = q.y - pt.y;
        // forbid FMA contraction: must match plain fp32 mul/mul/add rounding
        float d2 = __fadd_rn(__fmul_rn(dx, dx), __fmul_rn(dy, dy));
        unsigned long long key = ((unsigned long long)__float_as_uint(d2) << 32) | (unsigned)j;
        if (key < K[8]) {
            K[8] = key;
#pragma unroll
            for (int m = 8; m > 0; --m) {
                bool sw = K[m] < K[m - 1];
                unsigned long long a = sw ? K[m - 1] : K[m];
                unsigned long long c = sw ? K[m] : K[m - 1];
                K[m] = a; K[m - 1] = c;
            }
        }
    }

    // 9 extraction rounds: global min over the 16-lane group (keys are unique)
    int rec = -1;
#pragma unroll
    for (int r = 0; r < 9; ++r) {
        unsigned long long mn = K[0];
#pragma unroll
        for (int s = 1; s <= 8; s <<= 1) {
            unsigned long long o = shfl_xor_u64(mn, s);
            mn = (o < mn) ? o : mn;
        }
        if (K[0] == mn) {   // this lane owned the min: advance its sorted list
#pragma unroll
            for (int i = 0; i < 8; ++i) K[i] = K[i + 1];
            K[8] = ~0ULL;
        }
        if (r >= 1 && p == r - 1) rec = (int)(unsigned)mn;   // rounds 1..8 = neighbors
    }
    if (p < 8)
        idx[((size_t)b * NPTS + qq) * KNN + p] = rec;
}

// ---------------- gravnet1: gather 4-feat, mean, 4->32 relu -> 32; write xcat[0:34) ----------------
__global__ __launch_bounds__(256) void k_g1(const float* __restrict__ x,
                                            const int* __restrict__ idx,
                                            const float* __restrict__ w1,
                                            const float* __restrict__ b1,
                                            const float* __restrict__ w2,
                                            const float* __restrict__ b2,
                                            float* __restrict__ xcat) {
    __shared__ float sw1[4 * 32], sw2[32 * 32], sb1[32], sb2[32];
    int t = threadIdx.x;
    if (t < 128) sw1[t] = w1[t];
    for (int u = t; u < 1024; u += 256) sw2[u] = w2[u];
    if (t < 32) { sb1[t] = b1[t]; sb2[t] = b2[t]; }
    __syncthreads();

    int i = blockIdx.x * 256 + t;
    int b = i >> 12;
    int n = i & (NPTS - 1);
    const float* xb = x + (size_t)b * NPTS * FTOT;

    float agg[4] = {0.f, 0.f, 0.f, 0.f};
#pragma unroll
    for (int k = 0; k < KNN; ++k) {
        int nb = idx[(size_t)i * KNN + k];
        const float* f = xb + (size_t)nb * FTOT + 2;
        agg[0] += f[0]; agg[1] += f[1]; agg[2] += f[2]; agg[3] += f[3];
    }
#pragma unroll
    for (int k = 0; k < 4; ++k) agg[k] *= 0.125f;

    float h[32];
#pragma unroll
    for (int o = 0; o < 32; ++o) {
        float a = sb1[o];
#pragma unroll
        for (int k = 0; k < 4; ++k) a += agg[k] * sw1[k * 32 + o];
        h[o] = fmaxf(a, 0.f);
    }
    float* oc = xcat + (size_t)i * 68;
    oc[0] = xb[(size_t)n * FTOT];
    oc[1] = xb[(size_t)n * FTOT + 1];
#pragma unroll
    for (int o = 0; o < 32; ++o) {
        float a = sb2[o];
#pragma unroll
        for (int k = 0; k < 32; ++k) a += h[k] * sw2[k * 32 + o];
        oc[2 + o] = a;
    }
}

// ---------------- gravnet2: gather 32-feat (xcat cols 2..33), mean, 32->32 relu -> 32; write xcat[34:68) ----------------
__global__ __launch_bounds__(256) void k_g2(float* __restrict__ xcat,
                                            const int* __restrict__ idx,
                                            const float* __restrict__ w1,
                                            const float* __restrict__ b1,
                                            const float* __restrict__ w2,
                                            const float* __restrict__ b2) {
    __shared__ float sw1[32 * 32], sw2[32 * 32], sb1[32], sb2[32];
    int t = threadIdx.x;
    for (int u = t; u < 1024; u += 256) { sw1[u] = w1[u]; sw2[u] = w2[u]; }
    if (t < 32) { sb1[t] = b1[t]; sb2[t] = b2[t]; }
    __syncthreads();

    int i = blockIdx.x * 256 + t;
    int b = i >> 12;

    float agg[32];
#pragma unroll
    for (int j = 0; j < 32; ++j) agg[j] = 0.f;
#pragma unroll
    for (int k = 0; k < KNN; ++k) {
        int nb = idx[(size_t)i * KNN + k];
        const float* f = xcat + ((size_t)b * NPTS + nb) * 68 + 2;
#pragma unroll
        for (int j = 0; j < 32; ++j) agg[j] += f[j];
    }
#pragma unroll
    for (int j = 0; j < 32; ++j) agg[j] *= 0.125f;

    float h[32];
#pragma unroll
    for (int o = 0; o < 32; ++o) {
        float a = sb1[o];
#pragma unroll
        for (int k = 0; k < 32; ++k) a += agg[k] * sw1[k * 32 + o];
        h[o] = fmaxf(a, 0.f);
    }
    float* oc = xcat + (size_t)i * 68;
    oc[34] = oc[0];
    oc[35] = oc[1];
#pragma unroll
    for (int o = 0; o < 32; ++o) {
        float a = sb2[o];
#pragma unroll
        for (int k = 0; k < 32; ++k) a += h[k] * sw2[k * 32 + o];
        oc[36 + o] = a;
    }
}

// ---------------- d1: (BN,68) @ (68,128) + b, relu. block = 2 points x 128 outs ----------------
__global__ __launch_bounds__(256) void k_d1(const float* __restrict__ xcat,
                                            const float* __restrict__ w,
                                            const float* __restrict__ bias,
                                            float* __restrict__ h1) {
    __shared__ float sx[2][68];
    int t = threadIdx.x;
    int p0 = blockIdx.x * 2;
    if (t < 136) sx[t / 68][t % 68] = xcat[(size_t)p0 * 68 + t];
    __syncthreads();
    int pl = t >> 7, o = t & 127;
    float a = bias[o];
#pragma unroll 4
    for (int k = 0; k < 68; ++k) a += sx[pl][k] * w[k * 128 + o];
    h1[(size_t)(p0 + pl) * 128 + o] = fmaxf(a, 0.f);
}

// ---------------- d2: (BN,128) @ (128,64) + b, relu. block = 4 points x 64 outs ----------------
__global__ __launch_bounds__(256) void k_d2(const float* __restrict__ h1,
                                            const float* __restrict__ w,
                                            const float* __restrict__ bias,
                                            float* __restrict__ h2) {
    __shared__ float sx[4][128];
    int t = threadIdx.x;
    int p0 = blockIdx.x * 4;
    for (int u = t; u < 512; u += 256) sx[u >> 7][u & 127] = h1[(size_t)p0 * 128 + u];
    __syncthreads();
    int pl = t >> 6, o = t & 63;
    float a = bias[o];
#pragma unroll 4
    for (int k = 0; k < 128; ++k) a += sx[pl][k] * w[k * 64 + o];
    h2[(size_t)(p0 + pl) * 64 + o] = fmaxf(a, 0.f);
}

// ---------------- d3: (BN,64) @ (64,32) + b, relu. block = 8 points x 32 outs ----------------
__global__ __launch_bounds__(256) void k_d3(const float* __restrict__ h2,
                                            const float* __restrict__ w,
                                            const float* __restrict__ bias,
                                            float* __restrict__ h3) {
    __shared__ float sx[8][64];
    int t = threadIdx.x;
    int p0 = blockIdx.x * 8;
    for (int u = t; u < 512; u += 256) sx[u >> 6][u & 63] = h2[(size_t)p0 * 64 + u];
    __syncthreads();
    int pl = t >> 5, o = t & 31;
    float a = bias[o];
#pragma unroll 4
    for (int k = 0; k < 64; ++k) a += sx[pl][k] * w[k * 32 + o];
    h3[(size_t)(p0 + pl) * 32 + o] = fmaxf(a, 0.f);
}

// ---------------- bn2 + out: per-point dot over 32 ----------------
__global__ __launch_bounds__(256) void k_out(const float* __restrict__ h3,
                                             const float* __restrict__ g,
                                             const float* __restrict__ be,
                                             const float* __restrict__ m,
                                             const float* __restrict__ v,
                                             const float* __restrict__ ow,
                                             const float* __restrict__ ob,
                                             float* __restrict__ out) {
    int i = blockIdx.x * 256 + threadIdx.x;
    if (i >= BTOT * NPTS) return;
    float a = ob[0];
#pragma unroll
    for (int k = 0; k < 32; ++k) {
        float val = (h3[(size_t)i * 32 + k] - m[k]) * rsqrtf(v[k] + EPSV) * g[k] + be[k];
        a += val * ow[k];
    }
    out[i] = a;
}

extern "C" void kernel_launch(void* const* d_in, const int* in_sizes, int n_in,
                              void* d_out, int out_size, void* d_ws, size_t ws_size,
                              hipStream_t stream) {
    const float* inputs    = (const float*)d_in[0];
    const float* bn1_gamma = (const float*)d_in[1];
    const float* bn1_beta  = (const float*)d_in[2];
    const float* bn1_mean  = (const float*)d_in[3];
    const float* bn1_var   = (const float*)d_in[4];
    const float* g1_w1 = (const float*)d_in[5];
    const float* g1_b1 = (const float*)d_in[6];
    const float* g1_w2 = (const float*)d_in[7];
    const float* g1_b2 = (const float*)d_in[8];
    const float* g2_w1 = (const float*)d_in[9];
    const float* g2_b1 = (const float*)d_in[10];
    const float* g2_w2 = (const float*)d_in[11];
    const float* g2_b2 = (const float*)d_in[12];
    const float* d1_w = (const float*)d_in[13];
    const float* d1_b = (const float*)d_in[14];
    const float* d2_w = (const float*)d_in[15];
    const float* d2_b = (const float*)d_in[16];
    const float* d3_w = (const float*)d_in[17];
    const float* d3_b = (const float*)d_in[18];
    const float* bn2_gamma = (const float*)d_in[19];
    const float* bn2_beta  = (const float*)d_in[20];
    const float* bn2_mean  = (const float*)d_in[21];
    const float* bn2_var   = (const float*)d_in[22];
    const float* out_w = (const float*)d_in[23];
    const float* out_b = (const float*)d_in[24];
    float* out = (float*)d_out;

    const size_t BN = (size_t)BTOT * NPTS;
    char* ws = (char*)d_ws;
    size_t off = 0;
    auto alloc = [&](size_t bytes) { char* p = ws + off; off += (bytes + 255) & ~(size_t)255; return p; };
    float*  x    = (float*) alloc(BN * FTOT * sizeof(float));   // bn1 output
    float2* pos  = (float2*)alloc(BN * sizeof(float2));         // packed positions
    int*    idx  = (int*)   alloc(BN * KNN  * sizeof(int));     // knn indices (shared by g1,g2)
    float*  xcat = (float*) alloc(BN * 68   * sizeof(float));   // [x1 | x2]
    float*  h1   = (float*) alloc(BN * 128  * sizeof(float));
    float*  h2   = (float*) alloc(BN * 64   * sizeof(float));
    float*  h3   = (float*) alloc(BN * 32   * sizeof(float));
    (void)ws_size; (void)n_in; (void)in_sizes; (void)out_size;

    dim3 blk(256);
    k_bn1<<<dim3(64),   blk, 0, stream>>>(inputs, bn1_gamma, bn1_beta, bn1_mean, bn1_var, x, pos);
    k_knn<<<dim3(1024), blk, 0, stream>>>(pos, idx);
    k_g1 <<<dim3(64),   blk, 0, stream>>>(x, idx, g1_w1, g1_b1, g1_w2, g1_b2, xcat);
    k_g2 <<<dim3(64),   blk, 0, stream>>>(xcat, idx, g2_w1, g2_b1, g2_w2, g2_b2);
    k_d1 <<<dim3(8192), blk, 0, stream>>>(xcat, d1_w, d1_b, h1);
    k_d2 <<<dim3(4096), blk, 0, stream>>>(h1, d2_w, d2_b, h2);
    k_d3 <<<dim3(2048), blk, 0, stream>>>(h2, d3_w, d3_b, h3);
    k_out<<<dim3(64),   blk, 0, stream>>>(h3, bn2_gamma, bn2_beta, bn2_mean, bn2_var, out_w, out_b, out);
}

// Round 3
// 168.127 us; speedup vs baseline: 3.1517x; 1.9926x over previous
//
#include <hip/hip_runtime.h>
#include <hip/hip_bf16.h>

#define BTOT 4
#define NPTS 4096
#define FTOT 6
#define KNN 8
#define EPSV 1e-3f

__device__ __forceinline__ unsigned long long shfl_xor_u64(unsigned long long v, int mask) {
    unsigned lo = (unsigned)v, hi = (unsigned)(v >> 32);
    lo = (unsigned)__shfl_xor((int)lo, mask);
    hi = (unsigned)__shfl_xor((int)hi, mask);
    return ((unsigned long long)hi << 32) | lo;
}

// ---------------- bn1: x = (in - mean) * rsqrt(var+eps) * gamma + beta; also emit packed pos ----------------
__global__ __launch_bounds__(256) void k_bn1(const float* __restrict__ in,
                                             const float* __restrict__ g,
                                             const float* __restrict__ b,
                                             const float* __restrict__ m,
                                             const float* __restrict__ v,
                                             float* __restrict__ x,
                                             float2* __restrict__ pos) {
    int i = blockIdx.x * 256 + threadIdx.x;
    if (i >= BTOT * NPTS) return;
    float o[FTOT];
#pragma unroll
    for (int f = 0; f < FTOT; ++f) {
        float val = in[(size_t)i * FTOT + f];
        o[f] = (val - m[f]) * rsqrtf(v[f] + EPSV) * g[f] + b[f];
        x[(size_t)i * FTOT + f] = o[f];
    }
    pos[i] = make_float2(o[0], o[1]);
}

// ---------------- KNN v3: threshold-prefiltered exact top-9; 16 lanes per query ----------------
__global__ __launch_bounds__(256) void k_knn(const float2* __restrict__ posg,
                                             int* __restrict__ idx) {
    __shared__ float2 spos[NPTS];  // 32 KB
    int b = blockIdx.x >> 8;                   // 256 blocks per batch
    int q0 = (blockIdx.x & 255) << 4;          // 16 queries per block
    int t = threadIdx.x;
    const float2* pb = posg + (size_t)b * NPTS;
    for (int j = t; j < NPTS; j += 256) spos[j] = pb[j];
    __syncthreads();

    int lq = t >> 4;          // local query 0..15
    int p  = t & 15;          // partition lane 0..15
    int qq = q0 + lq;
    float2 q = spos[qq];

    // ---- pass 1: branchless per-lane lexicographic-min key over 256 candidates ----
    unsigned long long bm = ~0ULL;
#pragma unroll 8
    for (int jj = 0; jj < NPTS / 16; ++jj) {
        int j = (jj << 4) + p;
        float2 pt = spos[j];
        float dx = q.x - pt.x;
        float dy = q.y - pt.y;
        float d2 = __fadd_rn(__fmul_rn(dx, dx), __fmul_rn(dy, dy));  // no FMA contraction
        unsigned long long key = ((unsigned long long)__float_as_uint(d2) << 32) | (unsigned)j;
        bm = key < bm ? key : bm;   // strict <: ties keep earlier (smaller) j
    }

    // ---- threshold r = 9th smallest of the 16 lane minima (upper bound on global 9th key) ----
    unsigned long long KK = bm, r = 0;
#pragma unroll
    for (int rd = 0; rd < 9; ++rd) {
        unsigned long long mn = KK;
#pragma unroll
        for (int s = 1; s <= 8; s <<= 1) {
            unsigned long long o = shfl_xor_u64(mn, s);
            mn = (o < mn) ? o : mn;
        }
        if (KK == mn) KK = ~0ULL;   // owner retires (keys unique)
        r = mn;
    }
    unsigned long long sent = r + 1;  // keys unique: key <= r  <=>  key < sent

    // ---- pass 2: per-lane top-9 insertion, only for keys <= r (rare) ----
    unsigned long long K[9];
#pragma unroll
    for (int m = 0; m < 9; ++m) K[m] = sent;

#pragma unroll 4
    for (int jj = 0; jj < NPTS / 16; ++jj) {
        int j = (jj << 4) + p;
        float2 pt = spos[j];
        float dx = q.x - pt.x;
        float dy = q.y - pt.y;
        float d2 = __fadd_rn(__fmul_rn(dx, dx), __fmul_rn(dy, dy));
        unsigned long long key = ((unsigned long long)__float_as_uint(d2) << 32) | (unsigned)j;
        if (key < K[8]) {
            K[8] = key;
#pragma unroll
            for (int m = 8; m > 0; --m) {
                bool sw = K[m] < K[m - 1];
                unsigned long long a = sw ? K[m - 1] : K[m];
                unsigned long long c = sw ? K[m] : K[m - 1];
                K[m] = a; K[m - 1] = c;
            }
        }
    }

    // ---- 9 extraction rounds: global min over the 16-lane group (real keys unique, >=9 of them <= r) ----
    int rec = -1;
#pragma unroll
    for (int rd = 0; rd < 9; ++rd) {
        unsigned long long mn = K[0];
#pragma unroll
        for (int s = 1; s <= 8; s <<= 1) {
            unsigned long long o = shfl_xor_u64(mn, s);
            mn = (o < mn) ? o : mn;
        }
        if (K[0] == mn) {   // this lane owned the min: advance its sorted list
#pragma unroll
            for (int i = 0; i < 8; ++i) K[i] = K[i + 1];
            K[8] = ~0ULL;
        }
        if (rd >= 1 && p == rd - 1) rec = (int)(unsigned)mn;   // rounds 1..8 = the 8 neighbors
    }
    if (p < 8)
        idx[((size_t)b * NPTS + qq) * KNN + p] = rec;
}

// ---------------- gravnet1: gather 4-feat, mean, 4->32 relu -> 32; write xcat[0:34) ----------------
__global__ __launch_bounds__(256) void k_g1(const float* __restrict__ x,
                                            const int* __restrict__ idx,
                                            const float* __restrict__ w1,
                                            const float* __restrict__ b1,
                                            const float* __restrict__ w2,
                                            const float* __restrict__ b2,
                                            float* __restrict__ xcat) {
    __shared__ float sw1[4 * 32], sw2[32 * 32], sb1[32], sb2[32];
    int t = threadIdx.x;
    if (t < 128) sw1[t] = w1[t];
    for (int u = t; u < 1024; u += 256) sw2[u] = w2[u];
    if (t < 32) { sb1[t] = b1[t]; sb2[t] = b2[t]; }
    __syncthreads();

    int i = blockIdx.x * 256 + t;
    int b = i >> 12;
    int n = i & (NPTS - 1);
    const float* xb = x + (size_t)b * NPTS * FTOT;

    float agg[4] = {0.f, 0.f, 0.f, 0.f};
#pragma unroll
    for (int k = 0; k < KNN; ++k) {
        int nb = idx[(size_t)i * KNN + k];
        const float* f = xb + (size_t)nb * FTOT + 2;
        agg[0] += f[0]; agg[1] += f[1]; agg[2] += f[2]; agg[3] += f[3];
    }
#pragma unroll
    for (int k = 0; k < 4; ++k) agg[k] *= 0.125f;

    float h[32];
#pragma unroll
    for (int o = 0; o < 32; ++o) {
        float a = sb1[o];
#pragma unroll
        for (int k = 0; k < 4; ++k) a += agg[k] * sw1[k * 32 + o];
        h[o] = fmaxf(a, 0.f);
    }
    float* oc = xcat + (size_t)i * 68;
    oc[0] = xb[(size_t)n * FTOT];
    oc[1] = xb[(size_t)n * FTOT + 1];
#pragma unroll
    for (int o = 0; o < 32; ++o) {
        float a = sb2[o];
#pragma unroll
        for (int k = 0; k < 32; ++k) a += h[k] * sw2[k * 32 + o];
        oc[2 + o] = a;
    }
}

// ---------------- gravnet2: gather 32-feat (xcat cols 2..33), mean, 32->32 relu -> 32; write xcat[34:68) ----------------
__global__ __launch_bounds__(256) void k_g2(float* __restrict__ xcat,
                                            const int* __restrict__ idx,
                                            const float* __restrict__ w1,
                                            const float* __restrict__ b1,
                                            const float* __restrict__ w2,
                                            const float* __restrict__ b2) {
    __shared__ float sw1[32 * 32], sw2[32 * 32], sb1[32], sb2[32];
    int t = threadIdx.x;
    for (int u = t; u < 1024; u += 256) { sw1[u] = w1[u]; sw2[u] = w2[u]; }
    if (t < 32) { sb1[t] = b1[t]; sb2[t] = b2[t]; }
    __syncthreads();

    int i = blockIdx.x * 256 + t;
    int b = i >> 12;

    float agg[32];
#pragma unroll
    for (int j = 0; j < 32; ++j) agg[j] = 0.f;
#pragma unroll
    for (int k = 0; k < KNN; ++k) {
        int nb = idx[(size_t)i * KNN + k];
        const float* f = xcat + ((size_t)b * NPTS + nb) * 68 + 2;
#pragma unroll
        for (int j = 0; j < 32; ++j) agg[j] += f[j];
    }
#pragma unroll
    for (int j = 0; j < 32; ++j) agg[j] *= 0.125f;

    float h[32];
#pragma unroll
    for (int o = 0; o < 32; ++o) {
        float a = sb1[o];
#pragma unroll
        for (int k = 0; k < 32; ++k) a += agg[k] * sw1[k * 32 + o];
        h[o] = fmaxf(a, 0.f);
    }
    float* oc = xcat + (size_t)i * 68;
    oc[34] = oc[0];
    oc[35] = oc[1];
#pragma unroll
    for (int o = 0; o < 32; ++o) {
        float a = sb2[o];
#pragma unroll
        for (int k = 0; k < 32; ++k) a += h[k] * sw2[k * 32 + o];
        oc[36 + o] = a;
    }
}

// ---------------- d1: (BN,68) @ (68,128) + b, relu. block = 2 points x 128 outs ----------------
__global__ __launch_bounds__(256) void k_d1(const float* __restrict__ xcat,
                                            const float* __restrict__ w,
                                            const float* __restrict__ bias,
                                            float* __restrict__ h1) {
    __shared__ float sx[2][68];
    int t = threadIdx.x;
    int p0 = blockIdx.x * 2;
    if (t < 136) sx[t / 68][t % 68] = xcat[(size_t)p0 * 68 + t];
    __syncthreads();
    int pl = t >> 7, o = t & 127;
    float a = bias[o];
#pragma unroll 4
    for (int k = 0; k < 68; ++k) a += sx[pl][k] * w[k * 128 + o];
    h1[(size_t)(p0 + pl) * 128 + o] = fmaxf(a, 0.f);
}

// ---------------- d2: (BN,128) @ (128,64) + b, relu. block = 4 points x 64 outs ----------------
__global__ __launch_bounds__(256) void k_d2(const float* __restrict__ h1,
                                            const float* __restrict__ w,
                                            const float* __restrict__ bias,
                                            float* __restrict__ h2) {
    __shared__ float sx[4][128];
    int t = threadIdx.x;
    int p0 = blockIdx.x * 4;
    for (int u = t; u < 512; u += 256) sx[u >> 7][u & 127] = h1[(size_t)p0 * 128 + u];
    __syncthreads();
    int pl = t >> 6, o = t & 63;
    float a = bias[o];
#pragma unroll 4
    for (int k = 0; k < 128; ++k) a += sx[pl][k] * w[k * 64 + o];
    h2[(size_t)(p0 + pl) * 64 + o] = fmaxf(a, 0.f);
}

// ---------------- d3: (BN,64) @ (64,32) + b, relu. block = 8 points x 32 outs ----------------
__global__ __launch_bounds__(256) void k_d3(const float* __restrict__ h2,
                                            const float* __restrict__ w,
                                            const float* __restrict__ bias,
                                            float* __restrict__ h3) {
    __shared__ float sx[8][64];
    int t = threadIdx.x;
    int p0 = blockIdx.x * 8;
    for (int u = t; u < 512; u += 256) sx[u >> 6][u & 63] = h2[(size_t)p0 * 64 + u];
    __syncthreads();
    int pl = t >> 5, o = t & 31;
    float a = bias[o];
#pragma unroll 4
    for (int k = 0; k < 64; ++k) a += sx[pl][k] * w[k * 32 + o];
    h3[(size_t)(p0 + pl) * 32 + o] = fmaxf(a, 0.f);
}

// ---------------- bn2 + out: per-point dot over 32 ----------------
__global__ __launch_bounds__(256) void k_out(const float* __restrict__ h3,
                                             const float* __restrict__ g,
                                             const float* __restrict__ be,
                                             const float* __restrict__ m,
                                             const float* __restrict__ v,
                                             const float* __restrict__ ow,
                                             const float* __restrict__ ob,
                                             float* __restrict__ out) {
    int i = blockIdx.x * 256 + threadIdx.x;
    if (i >= BTOT * NPTS) return;
    float a = ob[0];
#pragma unroll
    for (int k = 0; k < 32; ++k) {
        float val = (h3[(size_t)i * 32 + k] - m[k]) * rsqrtf(v[k] + EPSV) * g[k] + be[k];
        a += val * ow[k];
    }
    out[i] = a;
}

extern "C" void kernel_launch(void* const* d_in, const int* in_sizes, int n_in,
                              void* d_out, int out_size, void* d_ws, size_t ws_size,
                              hipStream_t stream) {
    const float* inputs    = (const float*)d_in[0];
    const float* bn1_gamma = (const float*)d_in[1];
    const float* bn1_beta  = (const float*)d_in[2];
    const float* bn1_mean  = (const float*)d_in[3];
    const float* bn1_var   = (const float*)d_in[4];
    const float* g1_w1 = (const float*)d_in[5];
    const float* g1_b1 = (const float*)d_in[6];
    const float* g1_w2 = (const float*)d_in[7];
    const float* g1_b2 = (const float*)d_in[8];
    const float* g2_w1 = (const float*)d_in[9];
    const float* g2_b1 = (const float*)d_in[10];
    const float* g2_w2 = (const float*)d_in[11];
    const float* g2_b2 = (const float*)d_in[12];
    const float* d1_w = (const float*)d_in[13];
    const float* d1_b = (const float*)d_in[14];
    const float* d2_w = (const float*)d_in[15];
    const float* d2_b = (const float*)d_in[16];
    const float* d3_w = (const float*)d_in[17];
    const float* d3_b = (const float*)d_in[18];
    const float* bn2_gamma = (const float*)d_in[19];
    const float* bn2_beta  = (const float*)d_in[20];
    const float* bn2_mean  = (const float*)d_in[21];
    const float* bn2_var   = (const float*)d_in[22];
    const float* out_w = (const float*)d_in[23];
    const float* out_b = (const float*)d_in[24];
    float* out = (float*)d_out;

    const size_t BN = (size_t)BTOT * NPTS;
    char* ws = (char*)d_ws;
    size_t off = 0;
    auto alloc = [&](size_t bytes) { char* p = ws + off; off += (bytes + 255) & ~(size_t)255; return p; };
    float*  x    = (float*) alloc(BN * FTOT * sizeof(float));   // bn1 output
    float2* pos  = (float2*)alloc(BN * sizeof(float2));         // packed positions
    int*    idx  = (int*)   alloc(BN * KNN  * sizeof(int));     // knn indices (shared by g1,g2)
    float*  xcat = (float*) alloc(BN * 68   * sizeof(float));   // [x1 | x2]
    float*  h1   = (float*) alloc(BN * 128  * sizeof(float));
    float*  h2   = (float*) alloc(BN * 64   * sizeof(float));
    float*  h3   = (float*) alloc(BN * 32   * sizeof(float));
    (void)ws_size; (void)n_in; (void)in_sizes; (void)out_size;

    dim3 blk(256);
    k_bn1<<<dim3(64),   blk, 0, stream>>>(inputs, bn1_gamma, bn1_beta, bn1_mean, bn1_var, x, pos);
    k_knn<<<dim3(1024), blk, 0, stream>>>(pos, idx);
    k_g1 <<<dim3(64),   blk, 0, stream>>>(x, idx, g1_w1, g1_b1, g1_w2, g1_b2, xcat);
    k_g2 <<<dim3(64),   blk, 0, stream>>>(xcat, idx, g2_w1, g2_b1, g2_w2, g2_b2);
    k_d1 <<<dim3(8192), blk, 0, stream>>>(xcat, d1_w, d1_b, h1);
    k_d2 <<<dim3(4096), blk, 0, stream>>>(h1, d2_w, d2_b, h2);
    k_d3 <<<dim3(2048), blk, 0, stream>>>(h2, d3_w, d3_b, h3);
    k_out<<<dim3(64),   blk, 0, stream>>>(h3, bn2_gamma, bn2_beta, bn2_mean, bn2_var, out_w, out_b, out);
}

// Round 9
// 133.156 us; speedup vs baseline: 3.9794x; 1.2626x over previous
//
#include <hip/hip_runtime.h>
#include <hip/hip_bf16.h>

#define BTOT 4
#define NPTS 4096
#define FTOT 6
#define KNN 8
#define EPSV 1e-3f

__device__ __forceinline__ unsigned long long shfl_xor_u64(unsigned long long v, int mask) {
    unsigned lo = (unsigned)v, hi = (unsigned)(v >> 32);
    lo = (unsigned)__shfl_xor((int)lo, mask);
    hi = (unsigned)__shfl_xor((int)hi, mask);
    return ((unsigned long long)hi << 32) | lo;
}

// ---------------- bn1: identical to round 3 (passed) ----------------
__global__ __launch_bounds__(256) void k_bn1(const float* __restrict__ in,
                                             const float* __restrict__ g,
                                             const float* __restrict__ b,
                                             const float* __restrict__ m,
                                             const float* __restrict__ v,
                                             float* __restrict__ x,
                                             float2* __restrict__ pos) {
    int i = blockIdx.x * 256 + threadIdx.x;
    if (i >= BTOT * NPTS) return;
    float o[FTOT];
#pragma unroll
    for (int f = 0; f < FTOT; ++f) {
        float val = in[(size_t)i * FTOT + f];
        o[f] = (val - m[f]) * rsqrtf(v[f] + EPSV) * g[f] + b[f];
        x[(size_t)i * FTOT + f] = o[f];
    }
    pos[i] = make_float2(o[0], o[1]);
}

// ---------------- KNN v3: EXACT round-3 kernel (passed, 74 us) ----------------
__global__ __launch_bounds__(256) void k_knn(const float2* __restrict__ posg,
                                             int* __restrict__ idx) {
    __shared__ float2 spos[NPTS];  // 32 KB
    int b = blockIdx.x >> 8;                   // 256 blocks per batch
    int q0 = (blockIdx.x & 255) << 4;          // 16 queries per block
    int t = threadIdx.x;
    const float2* pb = posg + (size_t)b * NPTS;
    for (int j = t; j < NPTS; j += 256) spos[j] = pb[j];
    __syncthreads();

    int lq = t >> 4;          // local query 0..15
    int p  = t & 15;          // partition lane 0..15
    int qq = q0 + lq;
    float2 q = spos[qq];

    // ---- pass 1: branchless per-lane lexicographic-min key over 256 candidates ----
    unsigned long long bm = ~0ULL;
#pragma unroll 8
    for (int jj = 0; jj < NPTS / 16; ++jj) {
        int j = (jj << 4) + p;
        float2 pt = spos[j];
        float dx = q.x - pt.x;
        float dy = q.y - pt.y;
        float d2 = __fadd_rn(__fmul_rn(dx, dx), __fmul_rn(dy, dy));  // no FMA contraction
        unsigned long long key = ((unsigned long long)__float_as_uint(d2) << 32) | (unsigned)j;
        bm = key < bm ? key : bm;   // strict <: ties keep earlier (smaller) j
    }

    // ---- threshold r = 9th smallest of the 16 lane minima (upper bound on global 9th key) ----
    unsigned long long KK = bm, r = 0;
#pragma unroll
    for (int rd = 0; rd < 9; ++rd) {
        unsigned long long mn = KK;
#pragma unroll
        for (int s = 1; s <= 8; s <<= 1) {
            unsigned long long o = shfl_xor_u64(mn, s);
            mn = (o < mn) ? o : mn;
        }
        if (KK == mn) KK = ~0ULL;   // owner retires (keys unique)
        r = mn;
    }
    unsigned long long sent = r + 1;  // keys unique: key <= r  <=>  key < sent

    // ---- pass 2: per-lane top-9 insertion, only for keys <= r (rare) ----
    unsigned long long K[9];
#pragma unroll
    for (int m = 0; m < 9; ++m) K[m] = sent;

#pragma unroll 4
    for (int jj = 0; jj < NPTS / 16; ++jj) {
        int j = (jj << 4) + p;
        float2 pt = spos[j];
        float dx = q.x - pt.x;
        float dy = q.y - pt.y;
        float d2 = __fadd_rn(__fmul_rn(dx, dx), __fmul_rn(dy, dy));
        unsigned long long key = ((unsigned long long)__float_as_uint(d2) << 32) | (unsigned)j;
        if (key < K[8]) {
            K[8] = key;
#pragma unroll
            for (int m = 8; m > 0; --m) {
                bool sw = K[m] < K[m - 1];
                unsigned long long a = sw ? K[m - 1] : K[m];
                unsigned long long c = sw ? K[m] : K[m - 1];
                K[m] = a; K[m - 1] = c;
            }
        }
    }

    // ---- 9 extraction rounds: global min over the 16-lane group (real keys unique, >=9 of them <= r) ----
    int rec = -1;
#pragma unroll
    for (int rd = 0; rd < 9; ++rd) {
        unsigned long long mn = K[0];
#pragma unroll
        for (int s = 1; s <= 8; s <<= 1) {
            unsigned long long o = shfl_xor_u64(mn, s);
            mn = (o < mn) ? o : mn;
        }
        if (K[0] == mn) {   // this lane owned the min: advance its sorted list
#pragma unroll
            for (int i = 0; i < 8; ++i) K[i] = K[i + 1];
            K[8] = ~0ULL;
        }
        if (rd >= 1 && p == rd - 1) rec = (int)(unsigned)mn;   // rounds 1..8 = the 8 neighbors
    }
    if (p < 8)
        idx[((size_t)b * NPTS + qq) * KNN + p] = rec;
}

// ---------------- gravnet1: identical to round 3 (passed) ----------------
__global__ __launch_bounds__(256) void k_g1(const float* __restrict__ x,
                                            const int* __restrict__ idx,
                                            const float* __restrict__ w1,
                                            const float* __restrict__ b1,
                                            const float* __restrict__ w2,
                                            const float* __restrict__ b2,
                                            float* __restrict__ xcat) {
    __shared__ float sw1[4 * 32], sw2[32 * 32], sb1[32], sb2[32];
    int t = threadIdx.x;
    if (t < 128) sw1[t] = w1[t];
    for (int u = t; u < 1024; u += 256) sw2[u] = w2[u];
    if (t < 32) { sb1[t] = b1[t]; sb2[t] = b2[t]; }
    __syncthreads();

    int i = blockIdx.x * 256 + t;
    int b = i >> 12;
    int n = i & (NPTS - 1);
    const float* xb = x + (size_t)b * NPTS * FTOT;

    float agg[4] = {0.f, 0.f, 0.f, 0.f};
#pragma unroll
    for (int k = 0; k < KNN; ++k) {
        int nb = idx[(size_t)i * KNN + k];
        const float* f = xb + (size_t)nb * FTOT + 2;
        agg[0] += f[0]; agg[1] += f[1]; agg[2] += f[2]; agg[3] += f[3];
    }
#pragma unroll
    for (int k = 0; k < 4; ++k) agg[k] *= 0.125f;

    float h[32];
#pragma unroll
    for (int o = 0; o < 32; ++o) {
        float a = sb1[o];
#pragma unroll
        for (int k = 0; k < 4; ++k) a += agg[k] * sw1[k * 32 + o];
        h[o] = fmaxf(a, 0.f);
    }
    float* oc = xcat + (size_t)i * 68;
    oc[0] = xb[(size_t)n * FTOT];
    oc[1] = xb[(size_t)n * FTOT + 1];
#pragma unroll
    for (int o = 0; o < 32; ++o) {
        float a = sb2[o];
#pragma unroll
        for (int k = 0; k < 32; ++k) a += h[k] * sw2[k * 32 + o];
        oc[2 + o] = a;
    }
}

// ---------------- gravnet2: identical to round 3 (passed) ----------------
__global__ __launch_bounds__(256) void k_g2(float* __restrict__ xcat,
                                            const int* __restrict__ idx,
                                            const float* __restrict__ w1,
                                            const float* __restrict__ b1,
                                            const float* __restrict__ w2,
                                            const float* __restrict__ b2) {
    __shared__ float sw1[32 * 32], sw2[32 * 32], sb1[32], sb2[32];
    int t = threadIdx.x;
    for (int u = t; u < 1024; u += 256) { sw1[u] = w1[u]; sw2[u] = w2[u]; }
    if (t < 32) { sb1[t] = b1[t]; sb2[t] = b2[t]; }
    __syncthreads();

    int i = blockIdx.x * 256 + t;
    int b = i >> 12;

    float agg[32];
#pragma unroll
    for (int j = 0; j < 32; ++j) agg[j] = 0.f;
#pragma unroll
    for (int k = 0; k < KNN; ++k) {
        int nb = idx[(size_t)i * KNN + k];
        const float* f = xcat + ((size_t)b * NPTS + nb) * 68 + 2;
#pragma unroll
        for (int j = 0; j < 32; ++j) agg[j] += f[j];
    }
#pragma unroll
    for (int j = 0; j < 32; ++j) agg[j] *= 0.125f;

    float h[32];
#pragma unroll
    for (int o = 0; o < 32; ++o) {
        float a = sb1[o];
#pragma unroll
        for (int k = 0; k < 32; ++k) a += agg[k] * sw1[k * 32 + o];
        h[o] = fmaxf(a, 0.f);
    }
    float* oc = xcat + (size_t)i * 68;
    oc[34] = oc[0];
    oc[35] = oc[1];
#pragma unroll
    for (int o = 0; o < 32; ++o) {
        float a = sb2[o];
#pragma unroll
        for (int k = 0; k < 32; ++k) a += h[k] * sw2[k * 32 + o];
        oc[36 + o] = a;
    }
}

// ---------------- fused MLP: d1(68->128) d2(128->64) d3(64->32) bn2 out(32->1) ----------------
// block = 256 threads, tile = 32 points. lane owns 4 points x 4 outputs.
// All loads from d_in pointers are SCALAR; float4 only on LDS and d_out.
__global__ __launch_bounds__(256) void k_mlp(const float* __restrict__ xcat,
                                             const float* __restrict__ w1, const float* __restrict__ b1,
                                             const float* __restrict__ w2, const float* __restrict__ b2,
                                             const float* __restrict__ w3, const float* __restrict__ b3,
                                             const float* __restrict__ g,  const float* __restrict__ be,
                                             const float* __restrict__ mn, const float* __restrict__ vr,
                                             const float* __restrict__ ow, const float* __restrict__ ob,
                                             float* __restrict__ out) {
    __shared__ float xT[68][36];    // [k][point], rows 144B
    __shared__ float h1T[128][36];
    __shared__ float h2T[64][36];
    int t = threadIdx.x;
    int base = blockIdx.x * 32;

    for (int u = t; u < 32 * 68; u += 256) {
        int p = u / 68, k = u - p * 68;
        xT[k][p] = xcat[(size_t)(base + p) * 68 + k];
    }
    __syncthreads();

    int pq = t & 7;        // point quad 0..7 (32 points)
    int oq = t >> 3;       // output quad

    // ---- d1: K=68, N=128 (all 256 threads) ----
    {
        const float* bp = b1 + 4 * oq;
        float4 a0 = make_float4(bp[0], bp[0], bp[0], bp[0]);
        float4 a1 = make_float4(bp[1], bp[1], bp[1], bp[1]);
        float4 a2 = make_float4(bp[2], bp[2], bp[2], bp[2]);
        float4 a3 = make_float4(bp[3], bp[3], bp[3], bp[3]);
#pragma unroll 4
        for (int k = 0; k < 68; ++k) {
            float4 xv = *(const float4*)&xT[k][4 * pq];
            const float* wr = w1 + (size_t)k * 128 + 4 * oq;
            float w0v = wr[0], w1v = wr[1], w2v = wr[2], w3v = wr[3];
            a0.x += w0v * xv.x; a0.y += w0v * xv.y; a0.z += w0v * xv.z; a0.w += w0v * xv.w;
            a1.x += w1v * xv.x; a1.y += w1v * xv.y; a1.z += w1v * xv.z; a1.w += w1v * xv.w;
            a2.x += w2v * xv.x; a2.y += w2v * xv.y; a2.z += w2v * xv.z; a2.w += w2v * xv.w;
            a3.x += w3v * xv.x; a3.y += w3v * xv.y; a3.z += w3v * xv.z; a3.w += w3v * xv.w;
        }
        a0.x = fmaxf(a0.x, 0.f); a0.y = fmaxf(a0.y, 0.f); a0.z = fmaxf(a0.z, 0.f); a0.w = fmaxf(a0.w, 0.f);
        a1.x = fmaxf(a1.x, 0.f); a1.y = fmaxf(a1.y, 0.f); a1.z = fmaxf(a1.z, 0.f); a1.w = fmaxf(a1.w, 0.f);
        a2.x = fmaxf(a2.x, 0.f); a2.y = fmaxf(a2.y, 0.f); a2.z = fmaxf(a2.z, 0.f); a2.w = fmaxf(a2.w, 0.f);
        a3.x = fmaxf(a3.x, 0.f); a3.y = fmaxf(a3.y, 0.f); a3.z = fmaxf(a3.z, 0.f); a3.w = fmaxf(a3.w, 0.f);
        *(float4*)&h1T[4 * oq + 0][4 * pq] = a0;
        *(float4*)&h1T[4 * oq + 1][4 * pq] = a1;
        *(float4*)&h1T[4 * oq + 2][4 * pq] = a2;
        *(float4*)&h1T[4 * oq + 3][4 * pq] = a3;
    }
    __syncthreads();

    // ---- d2: K=128, N=64 (threads 0..127) ----
    if (t < 128) {
        const float* bp = b2 + 4 * oq;
        float4 a0 = make_float4(bp[0], bp[0], bp[0], bp[0]);
        float4 a1 = make_float4(bp[1], bp[1], bp[1], bp[1]);
        float4 a2 = make_float4(bp[2], bp[2], bp[2], bp[2]);
        float4 a3 = make_float4(bp[3], bp[3], bp[3], bp[3]);
#pragma unroll 4
        for (int k = 0; k < 128; ++k) {
            float4 xv = *(const float4*)&h1T[k][4 * pq];
            const float* wr = w2 + (size_t)k * 64 + 4 * oq;
            float w0v = wr[0], w1v = wr[1], w2v = wr[2], w3v = wr[3];
            a0.x += w0v * xv.x; a0.y += w0v * xv.y; a0.z += w0v * xv.z; a0.w += w0v * xv.w;
            a1.x += w1v * xv.x; a1.y += w1v * xv.y; a1.z += w1v * xv.z; a1.w += w1v * xv.w;
            a2.x += w2v * xv.x; a2.y += w2v * xv.y; a2.z += w2v * xv.z; a2.w += w2v * xv.w;
            a3.x += w3v * xv.x; a3.y += w3v * xv.y; a3.z += w3v * xv.z; a3.w += w3v * xv.w;
        }
        a0.x = fmaxf(a0.x, 0.f); a0.y = fmaxf(a0.y, 0.f); a0.z = fmaxf(a0.z, 0.f); a0.w = fmaxf(a0.w, 0.f);
        a1.x = fmaxf(a1.x, 0.f); a1.y = fmaxf(a1.y, 0.f); a1.z = fmaxf(a1.z, 0.f); a1.w = fmaxf(a1.w, 0.f);
        a2.x = fmaxf(a2.x, 0.f); a2.y = fmaxf(a2.y, 0.f); a2.z = fmaxf(a2.z, 0.f); a2.w = fmaxf(a2.w, 0.f);
        a3.x = fmaxf(a3.x, 0.f); a3.y = fmaxf(a3.y, 0.f); a3.z = fmaxf(a3.z, 0.f); a3.w = fmaxf(a3.w, 0.f);
        *(float4*)&h2T[4 * oq + 0][4 * pq] = a0;
        *(float4*)&h2T[4 * oq + 1][4 * pq] = a1;
        *(float4*)&h2T[4 * oq + 2][4 * pq] = a2;
        *(float4*)&h2T[4 * oq + 3][4 * pq] = a3;
    }
    __syncthreads();

    // ---- d3 + bn2 + out: K=64, N=32 (threads 0..63, one wave) ----
    if (t < 64) {
        const float* bp = b3 + 4 * oq;
        float4 a0 = make_float4(bp[0], bp[0], bp[0], bp[0]);
        float4 a1 = make_float4(bp[1], bp[1], bp[1], bp[1]);
        float4 a2 = make_float4(bp[2], bp[2], bp[2], bp[2]);
        float4 a3 = make_float4(bp[3], bp[3], bp[3], bp[3]);
#pragma unroll 4
        for (int k = 0; k < 64; ++k) {
            float4 xv = *(const float4*)&h2T[k][4 * pq];
            const float* wr = w3 + (size_t)k * 32 + 4 * oq;
            float w0v = wr[0], w1v = wr[1], w2v = wr[2], w3v = wr[3];
            a0.x += w0v * xv.x; a0.y += w0v * xv.y; a0.z += w0v * xv.z; a0.w += w0v * xv.w;
            a1.x += w1v * xv.x; a1.y += w1v * xv.y; a1.z += w1v * xv.z; a1.w += w1v * xv.w;
            a2.x += w2v * xv.x; a2.y += w2v * xv.y; a2.z += w2v * xv.z; a2.w += w2v * xv.w;
            a3.x += w3v * xv.x; a3.y += w3v * xv.y; a3.z += w3v * xv.z; a3.w += w3v * xv.w;
        }
        a0.x = fmaxf(a0.x, 0.f); a0.y = fmaxf(a0.y, 0.f); a0.z = fmaxf(a0.z, 0.f); a0.w = fmaxf(a0.w, 0.f);
        a1.x = fmaxf(a1.x, 0.f); a1.y = fmaxf(a1.y, 0.f); a1.z = fmaxf(a1.z, 0.f); a1.w = fmaxf(a1.w, 0.f);
        a2.x = fmaxf(a2.x, 0.f); a2.y = fmaxf(a2.y, 0.f); a2.z = fmaxf(a2.z, 0.f); a2.w = fmaxf(a2.w, 0.f);
        a3.x = fmaxf(a3.x, 0.f); a3.y = fmaxf(a3.y, 0.f); a3.z = fmaxf(a3.z, 0.f); a3.w = fmaxf(a3.w, 0.f);
        // bn2 + out_w fold (scalar param loads)
        int c0 = 4 * oq;
        float s0 = g[c0 + 0] * rsqrtf(vr[c0 + 0] + EPSV);
        float s1 = g[c0 + 1] * rsqrtf(vr[c0 + 1] + EPSV);
        float s2 = g[c0 + 2] * rsqrtf(vr[c0 + 2] + EPSV);
        float s3 = g[c0 + 3] * rsqrtf(vr[c0 + 3] + EPSV);
        float w0 = s0 * ow[c0 + 0], w1c = s1 * ow[c0 + 1];
        float w2c = s2 * ow[c0 + 2], w3c = s3 * ow[c0 + 3];
        float tt = (be[c0 + 0] - mn[c0 + 0] * s0) * ow[c0 + 0]
                 + (be[c0 + 1] - mn[c0 + 1] * s1) * ow[c0 + 1]
                 + (be[c0 + 2] - mn[c0 + 2] * s2) * ow[c0 + 2]
                 + (be[c0 + 3] - mn[c0 + 3] * s3) * ow[c0 + 3];
        float4 s;
        s.x = a0.x * w0 + a1.x * w1c + a2.x * w2c + a3.x * w3c;
        s.y = a0.y * w0 + a1.y * w1c + a2.y * w2c + a3.y * w3c;
        s.z = a0.z * w0 + a1.z * w1c + a2.z * w2c + a3.z * w3c;
        s.w = a0.w * w0 + a1.w * w1c + a2.w * w2c + a3.w * w3c;
#pragma unroll
        for (int msk = 8; msk <= 32; msk <<= 1) {
            s.x += __shfl_xor(s.x, msk);
            s.y += __shfl_xor(s.y, msk);
            s.z += __shfl_xor(s.z, msk);
            s.w += __shfl_xor(s.w, msk);
            tt  += __shfl_xor(tt,  msk);
        }
        if (oq == 0) {
            float c = tt + ob[0];
            *(float4*)(out + base + 4 * pq) = make_float4(s.x + c, s.y + c, s.z + c, s.w + c);
        }
    }
}

extern "C" void kernel_launch(void* const* d_in, const int* in_sizes, int n_in,
                              void* d_out, int out_size, void* d_ws, size_t ws_size,
                              hipStream_t stream) {
    const float* inputs    = (const float*)d_in[0];
    const float* bn1_gamma = (const float*)d_in[1];
    const float* bn1_beta  = (const float*)d_in[2];
    const float* bn1_mean  = (const float*)d_in[3];
    const float* bn1_var   = (const float*)d_in[4];
    const float* g1_w1 = (const float*)d_in[5];
    const float* g1_b1 = (const float*)d_in[6];
    const float* g1_w2 = (const float*)d_in[7];
    const float* g1_b2 = (const float*)d_in[8];
    const float* g2_w1 = (const float*)d_in[9];
    const float* g2_b1 = (const float*)d_in[10];
    const float* g2_w2 = (const float*)d_in[11];
    const float* g2_b2 = (const float*)d_in[12];
    const float* d1_w = (const float*)d_in[13];
    const float* d1_b = (const float*)d_in[14];
    const float* d2_w = (const float*)d_in[15];
    const float* d2_b = (const float*)d_in[16];
    const float* d3_w = (const float*)d_in[17];
    const float* d3_b = (const float*)d_in[18];
    const float* bn2_gamma = (const float*)d_in[19];
    const float* bn2_beta  = (const float*)d_in[20];
    const float* bn2_mean  = (const float*)d_in[21];
    const float* bn2_var   = (const float*)d_in[22];
    const float* out_w = (const float*)d_in[23];
    const float* out_b = (const float*)d_in[24];
    float* out = (float*)d_out;

    const size_t BN = (size_t)BTOT * NPTS;
    char* ws = (char*)d_ws;
    size_t off = 0;
    auto alloc = [&](size_t bytes) { char* p = ws + off; off += (bytes + 255) & ~(size_t)255; return p; };
    float*  x    = (float*) alloc(BN * FTOT * sizeof(float));   // bn1 output
    float2* pos  = (float2*)alloc(BN * sizeof(float2));         // packed positions
    int*    idx  = (int*)   alloc(BN * KNN  * sizeof(int));     // knn indices (shared by g1,g2)
    float*  xcat = (float*) alloc(BN * 68   * sizeof(float));   // [x1 | x2]
    (void)ws_size; (void)n_in; (void)in_sizes; (void)out_size;

    k_bn1<<<dim3(64),   dim3(256), 0, stream>>>(inputs, bn1_gamma, bn1_beta, bn1_mean, bn1_var, x, pos);
    k_knn<<<dim3(1024), dim3(256), 0, stream>>>(pos, idx);
    k_g1 <<<dim3(64),   dim3(256), 0, stream>>>(x, idx, g1_w1, g1_b1, g1_w2, g1_b2, xcat);
    k_g2 <<<dim3(64),   dim3(256), 0, stream>>>(xcat, idx, g2_w1, g2_b1, g2_w2, g2_b2);
    k_mlp<<<dim3(512),  dim3(256), 0, stream>>>(xcat, d1_w, d1_b, d2_w, d2_b, d3_w, d3_b,
                                                bn2_gamma, bn2_beta, bn2_mean, bn2_var,
                                                out_w, out_b, out);
}

// Round 10
// 119.329 us; speedup vs baseline: 4.4406x; 1.1159x over previous
//
#include <hip/hip_runtime.h>
#include <hip/hip_bf16.h>

#define BTOT 4
#define NPTS 4096
#define FTOT 6
#define KNN 8
#define EPSV 1e-3f

__device__ __forceinline__ unsigned long long shfl_xor_u64(unsigned long long v, int mask) {
    unsigned lo = (unsigned)v, hi = (unsigned)(v >> 32);
    lo = (unsigned)__shfl_xor((int)lo, mask);
    hi = (unsigned)__shfl_xor((int)hi, mask);
    return ((unsigned long long)hi << 32) | lo;
}

// ---------------- bn1: identical to round 3/9 (passed) ----------------
__global__ __launch_bounds__(256) void k_bn1(const float* __restrict__ in,
                                             const float* __restrict__ g,
                                             const float* __restrict__ b,
                                             const float* __restrict__ m,
                                             const float* __restrict__ v,
                                             float* __restrict__ x,
                                             float2* __restrict__ pos) {
    int i = blockIdx.x * 256 + threadIdx.x;
    if (i >= BTOT * NPTS) return;
    float o[FTOT];
#pragma unroll
    for (int f = 0; f < FTOT; ++f) {
        float val = in[(size_t)i * FTOT + f];
        o[f] = (val - m[f]) * rsqrtf(v[f] + EPSV) * g[f] + b[f];
        x[(size_t)i * FTOT + f] = o[f];
    }
    pos[i] = make_float2(o[0], o[1]);
}

// ---------------- KNN v5: v3 u64 algorithm, 32 lanes/query, 4-way pass-1 unroll, clamped output ----------------
__global__ __launch_bounds__(256) void k_knn(const float2* __restrict__ posg,
                                             int* __restrict__ idx) {
    __shared__ float2 spos[NPTS];  // 32 KB
    int b  = blockIdx.x >> 9;                 // 512 blocks per batch
    int q0 = (blockIdx.x & 511) << 3;         // 8 queries per block
    int t  = threadIdx.x;
    const float2* pb = posg + (size_t)b * NPTS;
    for (int j = t; j < NPTS; j += 256) spos[j] = pb[j];
    __syncthreads();

    int lq = t >> 5;          // local query 0..7
    int p  = t & 31;          // partition lane 0..31
    int qq = q0 + lq;
    float2 q = spos[qq];

    // ---- pass 1: per-lane lexicographic-min u64 key, 4 independent accumulators (min is associative) ----
    unsigned long long bm0 = ~0ULL, bm1 = ~0ULL, bm2 = ~0ULL, bm3 = ~0ULL;
    for (int jj = 0; jj < NPTS / 32; jj += 4) {
        int j0 = ((jj + 0) << 5) + p;
        int j1 = ((jj + 1) << 5) + p;
        int j2 = ((jj + 2) << 5) + p;
        int j3 = ((jj + 3) << 5) + p;
        float2 p0 = spos[j0], p1 = spos[j1], p2 = spos[j2], p3 = spos[j3];
        float d0 = __fadd_rn(__fmul_rn(q.x - p0.x, q.x - p0.x), __fmul_rn(q.y - p0.y, q.y - p0.y));
        float d1 = __fadd_rn(__fmul_rn(q.x - p1.x, q.x - p1.x), __fmul_rn(q.y - p1.y, q.y - p1.y));
        float d2 = __fadd_rn(__fmul_rn(q.x - p2.x, q.x - p2.x), __fmul_rn(q.y - p2.y, q.y - p2.y));
        float d3 = __fadd_rn(__fmul_rn(q.x - p3.x, q.x - p3.x), __fmul_rn(q.y - p3.y, q.y - p3.y));
        unsigned long long k0 = ((unsigned long long)__float_as_uint(d0) << 32) | (unsigned)j0;
        unsigned long long k1 = ((unsigned long long)__float_as_uint(d1) << 32) | (unsigned)j1;
        unsigned long long k2 = ((unsigned long long)__float_as_uint(d2) << 32) | (unsigned)j2;
        unsigned long long k3 = ((unsigned long long)__float_as_uint(d3) << 32) | (unsigned)j3;
        bm0 = k0 < bm0 ? k0 : bm0;
        bm1 = k1 < bm1 ? k1 : bm1;
        bm2 = k2 < bm2 ? k2 : bm2;
        bm3 = k3 < bm3 ? k3 : bm3;
    }
    unsigned long long bma = bm0 < bm1 ? bm0 : bm1;
    unsigned long long bmb = bm2 < bm3 ? bm2 : bm3;
    unsigned long long bm  = bma < bmb ? bma : bmb;

    // ---- threshold r = 9th smallest of the 32 lane-min keys (upper bound on global 9th key) ----
    unsigned long long KK = bm, r = 0;
#pragma unroll
    for (int rd = 0; rd < 9; ++rd) {
        unsigned long long mn = KK;
#pragma unroll
        for (int s = 1; s <= 16; s <<= 1) {
            unsigned long long o = shfl_xor_u64(mn, s);
            mn = (o < mn) ? o : mn;
        }
        if (KK == mn) KK = ~0ULL;   // owner retires (keys unique)
        r = mn;
    }
    unsigned long long sent = r + 1;  // keys unique: key <= r  <=>  key < sent

    // ---- pass 2: per-lane top-9 insertion, only for keys < sent (rare) ----
    unsigned long long K[9];
#pragma unroll
    for (int m = 0; m < 9; ++m) K[m] = sent;

#pragma unroll 4
    for (int jj = 0; jj < NPTS / 32; ++jj) {
        int j = (jj << 5) + p;
        float2 pt = spos[j];
        float dx = q.x - pt.x;
        float dy = q.y - pt.y;
        float d2 = __fadd_rn(__fmul_rn(dx, dx), __fmul_rn(dy, dy));  // no FMA contraction
        unsigned long long key = ((unsigned long long)__float_as_uint(d2) << 32) | (unsigned)j;
        if (key < K[8]) {
            K[8] = key;
#pragma unroll
            for (int m = 8; m > 0; --m) {
                bool sw = K[m] < K[m - 1];
                unsigned long long a = sw ? K[m - 1] : K[m];
                unsigned long long c = sw ? K[m] : K[m - 1];
                K[m] = a; K[m - 1] = c;
            }
        }
    }

    // ---- 9 extraction rounds: global min over the 32-lane group (>=9 real keys < sent) ----
    int rec = qq;   // inert when correct; keeps downstream in-range if not
#pragma unroll
    for (int rd = 0; rd < 9; ++rd) {
        unsigned long long mn = K[0];
#pragma unroll
        for (int s = 1; s <= 16; s <<= 1) {
            unsigned long long o = shfl_xor_u64(mn, s);
            mn = (o < mn) ? o : mn;
        }
        if (K[0] == mn) {   // this lane owned the min: advance its sorted list
#pragma unroll
            for (int i = 0; i < 8; ++i) K[i] = K[i + 1];
            K[8] = ~0ULL;
        }
        if (rd >= 1 && p == rd - 1) rec = (int)(unsigned)mn;   // rounds 1..8 = the 8 neighbors
    }
    rec &= (NPTS - 1);   // hard-mask to [0,4096): downstream gathers can never fault
    if (p < 8)
        idx[((size_t)b * NPTS + qq) * KNN + p] = rec;
}

// ---------------- gravnet1: round-3 math, spread to 256 blocks x 64 threads ----------------
__global__ __launch_bounds__(64) void k_g1(const float* __restrict__ x,
                                           const int* __restrict__ idx,
                                           const float* __restrict__ w1,
                                           const float* __restrict__ b1,
                                           const float* __restrict__ w2,
                                           const float* __restrict__ b2,
                                           float* __restrict__ xcat) {
    __shared__ float sw1[4 * 32], sw2[32 * 32], sb1[32], sb2[32];
    int t = threadIdx.x;
    for (int u = t; u < 128; u += 64) sw1[u] = w1[u];
    for (int u = t; u < 1024; u += 64) sw2[u] = w2[u];
    if (t < 32) { sb1[t] = b1[t]; sb2[t] = b2[t]; }
    __syncthreads();

    int i = blockIdx.x * 64 + t;
    int b = i >> 12;
    int n = i & (NPTS - 1);
    const float* xb = x + (size_t)b * NPTS * FTOT;

    float agg[4] = {0.f, 0.f, 0.f, 0.f};
#pragma unroll
    for (int k = 0; k < KNN; ++k) {
        int nb = idx[(size_t)i * KNN + k];
        const float* f = xb + (size_t)nb * FTOT + 2;
        agg[0] += f[0]; agg[1] += f[1]; agg[2] += f[2]; agg[3] += f[3];
    }
#pragma unroll
    for (int k = 0; k < 4; ++k) agg[k] *= 0.125f;

    float h[32];
#pragma unroll
    for (int o = 0; o < 32; ++o) {
        float a = sb1[o];
#pragma unroll
        for (int k = 0; k < 4; ++k) a += agg[k] * sw1[k * 32 + o];
        h[o] = fmaxf(a, 0.f);
    }
    float* oc = xcat + (size_t)i * 68;
    oc[0] = xb[(size_t)n * FTOT];
    oc[1] = xb[(size_t)n * FTOT + 1];
#pragma unroll
    for (int o = 0; o < 32; ++o) {
        float a = sb2[o];
#pragma unroll
        for (int k = 0; k < 32; ++k) a += h[k] * sw2[k * 32 + o];
        oc[2 + o] = a;
    }
}

// ---------------- gravnet2: round-3 math, spread to 256 blocks x 64 threads ----------------
__global__ __launch_bounds__(64) void k_g2(float* __restrict__ xcat,
                                           const int* __restrict__ idx,
                                           const float* __restrict__ w1,
                                           const float* __restrict__ b1,
                                           const float* __restrict__ w2,
                                           const float* __restrict__ b2) {
    __shared__ float sw1[32 * 32], sw2[32 * 32], sb1[32], sb2[32];
    int t = threadIdx.x;
    for (int u = t; u < 1024; u += 64) { sw1[u] = w1[u]; sw2[u] = w2[u]; }
    if (t < 32) { sb1[t] = b1[t]; sb2[t] = b2[t]; }
    __syncthreads();

    int i = blockIdx.x * 64 + t;
    int b = i >> 12;

    float agg[32];
#pragma unroll
    for (int j = 0; j < 32; ++j) agg[j] = 0.f;
#pragma unroll
    for (int k = 0; k < KNN; ++k) {
        int nb = idx[(size_t)i * KNN + k];
        const float* f = xcat + ((size_t)b * NPTS + nb) * 68 + 2;
#pragma unroll
        for (int j = 0; j < 32; ++j) agg[j] += f[j];
    }
#pragma unroll
    for (int j = 0; j < 32; ++j) agg[j] *= 0.125f;

    float h[32];
#pragma unroll
    for (int o = 0; o < 32; ++o) {
        float a = sb1[o];
#pragma unroll
        for (int k = 0; k < 32; ++k) a += agg[k] * sw1[k * 32 + o];
        h[o] = fmaxf(a, 0.f);
    }
    float* oc = xcat + (size_t)i * 68;
    oc[34] = oc[0];
    oc[35] = oc[1];
#pragma unroll
    for (int o = 0; o < 32; ++o) {
        float a = sb2[o];
#pragma unroll
        for (int k = 0; k < 32; ++k) a += h[k] * sw2[k * 32 + o];
        oc[36 + o] = a;
    }
}

// ---------------- fused MLP: identical to round 9 (passed) ----------------
__global__ __launch_bounds__(256) void k_mlp(const float* __restrict__ xcat,
                                             const float* __restrict__ w1, const float* __restrict__ b1,
                                             const float* __restrict__ w2, const float* __restrict__ b2,
                                             const float* __restrict__ w3, const float* __restrict__ b3,
                                             const float* __restrict__ g,  const float* __restrict__ be,
                                             const float* __restrict__ mn, const float* __restrict__ vr,
                                             const float* __restrict__ ow, const float* __restrict__ ob,
                                             float* __restrict__ out) {
    __shared__ float xT[68][36];
    __shared__ float h1T[128][36];
    __shared__ float h2T[64][36];
    int t = threadIdx.x;
    int base = blockIdx.x * 32;

    for (int u = t; u < 32 * 68; u += 256) {
        int p = u / 68, k = u - p * 68;
        xT[k][p] = xcat[(size_t)(base + p) * 68 + k];
    }
    __syncthreads();

    int pq = t & 7;
    int oq = t >> 3;

    {
        const float* bp = b1 + 4 * oq;
        float4 a0 = make_float4(bp[0], bp[0], bp[0], bp[0]);
        float4 a1 = make_float4(bp[1], bp[1], bp[1], bp[1]);
        float4 a2 = make_float4(bp[2], bp[2], bp[2], bp[2]);
        float4 a3 = make_float4(bp[3], bp[3], bp[3], bp[3]);
#pragma unroll 4
        for (int k = 0; k < 68; ++k) {
            float4 xv = *(const float4*)&xT[k][4 * pq];
            const float* wr = w1 + (size_t)k * 128 + 4 * oq;
            float w0v = wr[0], w1v = wr[1], w2v = wr[2], w3v = wr[3];
            a0.x += w0v * xv.x; a0.y += w0v * xv.y; a0.z += w0v * xv.z; a0.w += w0v * xv.w;
            a1.x += w1v * xv.x; a1.y += w1v * xv.y; a1.z += w1v * xv.z; a1.w += w1v * xv.w;
            a2.x += w2v * xv.x; a2.y += w2v * xv.y; a2.z += w2v * xv.z; a2.w += w2v * xv.w;
            a3.x += w3v * xv.x; a3.y += w3v * xv.y; a3.z += w3v * xv.z; a3.w += w3v * xv.w;
        }
        a0.x = fmaxf(a0.x, 0.f); a0.y = fmaxf(a0.y, 0.f); a0.z = fmaxf(a0.z, 0.f); a0.w = fmaxf(a0.w, 0.f);
        a1.x = fmaxf(a1.x, 0.f); a1.y = fmaxf(a1.y, 0.f); a1.z = fmaxf(a1.z, 0.f); a1.w = fmaxf(a1.w, 0.f);
        a2.x = fmaxf(a2.x, 0.f); a2.y = fmaxf(a2.y, 0.f); a2.z = fmaxf(a2.z, 0.f); a2.w = fmaxf(a2.w, 0.f);
        a3.x = fmaxf(a3.x, 0.f); a3.y = fmaxf(a3.y, 0.f); a3.z = fmaxf(a3.z, 0.f); a3.w = fmaxf(a3.w, 0.f);
        *(float4*)&h1T[4 * oq + 0][4 * pq] = a0;
        *(float4*)&h1T[4 * oq + 1][4 * pq] = a1;
        *(float4*)&h1T[4 * oq + 2][4 * pq] = a2;
        *(float4*)&h1T[4 * oq + 3][4 * pq] = a3;
    }
    __syncthreads();

    if (t < 128) {
        const float* bp = b2 + 4 * oq;
        float4 a0 = make_float4(bp[0], bp[0], bp[0], bp[0]);
        float4 a1 = make_float4(bp[1], bp[1], bp[1], bp[1]);
        float4 a2 = make_float4(bp[2], bp[2], bp[2], bp[2]);
        float4 a3 = make_float4(bp[3], bp[3], bp[3], bp[3]);
#pragma unroll 4
        for (int k = 0; k < 128; ++k) {
            float4 xv = *(const float4*)&h1T[k][4 * pq];
            const float* wr = w2 + (size_t)k * 64 + 4 * oq;
            float w0v = wr[0], w1v = wr[1], w2v = wr[2], w3v = wr[3];
            a0.x += w0v * xv.x; a0.y += w0v * xv.y; a0.z += w0v * xv.z; a0.w += w0v * xv.w;
            a1.x += w1v * xv.x; a1.y += w1v * xv.y; a1.z += w1v * xv.z; a1.w += w1v * xv.w;
            a2.x += w2v * xv.x; a2.y += w2v * xv.y; a2.z += w2v * xv.z; a2.w += w2v * xv.w;
            a3.x += w3v * xv.x; a3.y += w3v * xv.y; a3.z += w3v * xv.z; a3.w += w3v * xv.w;
        }
        a0.x = fmaxf(a0.x, 0.f); a0.y = fmaxf(a0.y, 0.f); a0.z = fmaxf(a0.z, 0.f); a0.w = fmaxf(a0.w, 0.f);
        a1.x = fmaxf(a1.x, 0.f); a1.y = fmaxf(a1.y, 0.f); a1.z = fmaxf(a1.z, 0.f); a1.w = fmaxf(a1.w, 0.f);
        a2.x = fmaxf(a2.x, 0.f); a2.y = fmaxf(a2.y, 0.f); a2.z = fmaxf(a2.z, 0.f); a2.w = fmaxf(a2.w, 0.f);
        a3.x = fmaxf(a3.x, 0.f); a3.y = fmaxf(a3.y, 0.f); a3.z = fmaxf(a3.z, 0.f); a3.w = fmaxf(a3.w, 0.f);
        *(float4*)&h2T[4 * oq + 0][4 * pq] = a0;
        *(float4*)&h2T[4 * oq + 1][4 * pq] = a1;
        *(float4*)&h2T[4 * oq + 2][4 * pq] = a2;
        *(float4*)&h2T[4 * oq + 3][4 * pq] = a3;
    }
    __syncthreads();

    if (t < 64) {
        const float* bp = b3 + 4 * oq;
        float4 a0 = make_float4(bp[0], bp[0], bp[0], bp[0]);
        float4 a1 = make_float4(bp[1], bp[1], bp[1], bp[1]);
        float4 a2 = make_float4(bp[2], bp[2], bp[2], bp[2]);
        float4 a3 = make_float4(bp[3], bp[3], bp[3], bp[3]);
#pragma unroll 4
        for (int k = 0; k < 64; ++k) {
            float4 xv = *(const float4*)&h2T[k][4 * pq];
            const float* wr = w3 + (size_t)k * 32 + 4 * oq;
            float w0v = wr[0], w1v = wr[1], w2v = wr[2], w3v = wr[3];
            a0.x += w0v * xv.x; a0.y += w0v * xv.y; a0.z += w0v * xv.z; a0.w += w0v * xv.w;
            a1.x += w1v * xv.x; a1.y += w1v * xv.y; a1.z += w1v * xv.z; a1.w += w1v * xv.w;
            a2.x += w2v * xv.x; a2.y += w2v * xv.y; a2.z += w2v * xv.z; a2.w += w2v * xv.w;
            a3.x += w3v * xv.x; a3.y += w3v * xv.y; a3.z += w3v * xv.z; a3.w += w3v * xv.w;
        }
        a0.x = fmaxf(a0.x, 0.f); a0.y = fmaxf(a0.y, 0.f); a0.z = fmaxf(a0.z, 0.f); a0.w = fmaxf(a0.w, 0.f);
        a1.x = fmaxf(a1.x, 0.f); a1.y = fmaxf(a1.y, 0.f); a1.z = fmaxf(a1.z, 0.f); a1.w = fmaxf(a1.w, 0.f);
        a2.x = fmaxf(a2.x, 0.f); a2.y = fmaxf(a2.y, 0.f); a2.z = fmaxf(a2.z, 0.f); a2.w = fmaxf(a2.w, 0.f);
        a3.x = fmaxf(a3.x, 0.f); a3.y = fmaxf(a3.y, 0.f); a3.z = fmaxf(a3.z, 0.f); a3.w = fmaxf(a3.w, 0.f);
        int c0 = 4 * oq;
        float s0 = g[c0 + 0] * rsqrtf(vr[c0 + 0] + EPSV);
        float s1 = g[c0 + 1] * rsqrtf(vr[c0 + 1] + EPSV);
        float s2 = g[c0 + 2] * rsqrtf(vr[c0 + 2] + EPSV);
        float s3 = g[c0 + 3] * rsqrtf(vr[c0 + 3] + EPSV);
        float w0 = s0 * ow[c0 + 0], w1c = s1 * ow[c0 + 1];
        float w2c = s2 * ow[c0 + 2], w3c = s3 * ow[c0 + 3];
        float tt = (be[c0 + 0] - mn[c0 + 0] * s0) * ow[c0 + 0]
                 + (be[c0 + 1] - mn[c0 + 1] * s1) * ow[c0 + 1]
                 + (be[c0 + 2] - mn[c0 + 2] * s2) * ow[c0 + 2]
                 + (be[c0 + 3] - mn[c0 + 3] * s3) * ow[c0 + 3];
        float4 s;
        s.x = a0.x * w0 + a1.x * w1c + a2.x * w2c + a3.x * w3c;
        s.y = a0.y * w0 + a1.y * w1c + a2.y * w2c + a3.y * w3c;
        s.z = a0.z * w0 + a1.z * w1c + a2.z * w2c + a3.z * w3c;
        s.w = a0.w * w0 + a1.w * w1c + a2.w * w2c + a3.w * w3c;
#pragma unroll
        for (int msk = 8; msk <= 32; msk <<= 1) {
            s.x += __shfl_xor(s.x, msk);
            s.y += __shfl_xor(s.y, msk);
            s.z += __shfl_xor(s.z, msk);
            s.w += __shfl_xor(s.w, msk);
            tt  += __shfl_xor(tt,  msk);
        }
        if (oq == 0) {
            float c = tt + ob[0];
            *(float4*)(out + base + 4 * pq) = make_float4(s.x + c, s.y + c, s.z + c, s.w + c);
        }
    }
}

extern "C" void kernel_launch(void* const* d_in, const int* in_sizes, int n_in,
                              void* d_out, int out_size, void* d_ws, size_t ws_size,
                              hipStream_t stream) {
    const float* inputs    = (const float*)d_in[0];
    const float* bn1_gamma = (const float*)d_in[1];
    const float* bn1_beta  = (const float*)d_in[2];
    const float* bn1_mean  = (const float*)d_in[3];
    const float* bn1_var   = (const float*)d_in[4];
    const float* g1_w1 = (const float*)d_in[5];
    const float* g1_b1 = (const float*)d_in[6];
    const float* g1_w2 = (const float*)d_in[7];
    const float* g1_b2 = (const float*)d_in[8];
    const float* g2_w1 = (const float*)d_in[9];
    const float* g2_b1 = (const float*)d_in[10];
    const float* g2_w2 = (const float*)d_in[11];
    const float* g2_b2 = (const float*)d_in[12];
    const float* d1_w = (const float*)d_in[13];
    const float* d1_b = (const float*)d_in[14];
    const float* d2_w = (const float*)d_in[15];
    const float* d2_b = (const float*)d_in[16];
    const float* d3_w = (const float*)d_in[17];
    const float* d3_b = (const float*)d_in[18];
    const float* bn2_gamma = (const float*)d_in[19];
    const float* bn2_beta  = (const float*)d_in[20];
    const float* bn2_mean  = (const float*)d_in[21];
    const float* bn2_var   = (const float*)d_in[22];
    const float* out_w = (const float*)d_in[23];
    const float* out_b = (const float*)d_in[24];
    float* out = (float*)d_out;

    const size_t BN = (size_t)BTOT * NPTS;
    char* ws = (char*)d_ws;
    size_t off = 0;
    auto alloc = [&](size_t bytes) { char* p = ws + off; off += (bytes + 255) & ~(size_t)255; return p; };
    float*  x    = (float*) alloc(BN * FTOT * sizeof(float));
    float2* pos  = (float2*)alloc(BN * sizeof(float2));
    int*    idx  = (int*)   alloc(BN * KNN  * sizeof(int));
    float*  xcat = (float*) alloc(BN * 68   * sizeof(float));
    (void)ws_size; (void)n_in; (void)in_sizes; (void)out_size;

    k_bn1<<<dim3(64),   dim3(256), 0, stream>>>(inputs, bn1_gamma, bn1_beta, bn1_mean, bn1_var, x, pos);
    k_knn<<<dim3(2048), dim3(256), 0, stream>>>(pos, idx);
    k_g1 <<<dim3(256),  dim3(64),  0, stream>>>(x, idx, g1_w1, g1_b1, g1_w2, g1_b2, xcat);
    k_g2 <<<dim3(256),  dim3(64),  0, stream>>>(xcat, idx, g2_w1, g2_b1, g2_w2, g2_b2);
    k_mlp<<<dim3(512),  dim3(256), 0, stream>>>(xcat, d1_w, d1_b, d2_w, d2_b, d3_w, d3_b,
                                                bn2_gamma, bn2_beta, bn2_mean, bn2_var,
                                                out_w, out_b, out);
}

// Round 11
// 109.376 us; speedup vs baseline: 4.8446x; 1.0910x over previous
//
#include <hip/hip_runtime.h>
#include <hip/hip_bf16.h>

#define BTOT 4
#define NPTS 4096
#define FTOT 6
#define KNN 8
#define EPSV 1e-3f

__device__ __forceinline__ unsigned long long shfl_xor_u64(unsigned long long v, int mask) {
    unsigned lo = (unsigned)v, hi = (unsigned)(v >> 32);
    lo = (unsigned)__shfl_xor((int)lo, mask);
    hi = (unsigned)__shfl_xor((int)hi, mask);
    return ((unsigned long long)hi << 32) | lo;
}

// ---------------- bn1: identical to round 10 (passed) ----------------
__global__ __launch_bounds__(256) void k_bn1(const float* __restrict__ in,
                                             const float* __restrict__ g,
                                             const float* __restrict__ b,
                                             const float* __restrict__ m,
                                             const float* __restrict__ v,
                                             float* __restrict__ x,
                                             float2* __restrict__ pos) {
    int i = blockIdx.x * 256 + threadIdx.x;
    if (i >= BTOT * NPTS) return;
    float o[FTOT];
#pragma unroll
    for (int f = 0; f < FTOT; ++f) {
        float val = in[(size_t)i * FTOT + f];
        o[f] = (val - m[f]) * rsqrtf(v[f] + EPSV) * g[f] + b[f];
        x[(size_t)i * FTOT + f] = o[f];
    }
    pos[i] = make_float2(o[0], o[1]);
}

// ---------------- KNN v6: v5 body (passed) at 512 threads/block = 16 queries x 32 lanes ----------------
__global__ __launch_bounds__(512) void k_knn(const float2* __restrict__ posg,
                                             int* __restrict__ idx) {
    __shared__ float2 spos[NPTS];  // 32 KB
    int b  = blockIdx.x >> 8;                 // 256 blocks per batch
    int q0 = (blockIdx.x & 255) << 4;         // 16 queries per block
    int t  = threadIdx.x;
    const float2* pb = posg + (size_t)b * NPTS;
    for (int j = t; j < NPTS; j += 512) spos[j] = pb[j];
    __syncthreads();

    int lq = t >> 5;          // local query 0..15
    int p  = t & 31;          // partition lane 0..31
    int qq = q0 + lq;
    float2 q = spos[qq];

    // ---- pass 1: per-lane lexicographic-min u64 key, 4 independent accumulators (min is associative) ----
    unsigned long long bm0 = ~0ULL, bm1 = ~0ULL, bm2 = ~0ULL, bm3 = ~0ULL;
    for (int jj = 0; jj < NPTS / 32; jj += 4) {
        int j0 = ((jj + 0) << 5) + p;
        int j1 = ((jj + 1) << 5) + p;
        int j2 = ((jj + 2) << 5) + p;
        int j3 = ((jj + 3) << 5) + p;
        float2 p0 = spos[j0], p1 = spos[j1], p2 = spos[j2], p3 = spos[j3];
        float d0 = __fadd_rn(__fmul_rn(q.x - p0.x, q.x - p0.x), __fmul_rn(q.y - p0.y, q.y - p0.y));
        float d1 = __fadd_rn(__fmul_rn(q.x - p1.x, q.x - p1.x), __fmul_rn(q.y - p1.y, q.y - p1.y));
        float d2 = __fadd_rn(__fmul_rn(q.x - p2.x, q.x - p2.x), __fmul_rn(q.y - p2.y, q.y - p2.y));
        float d3 = __fadd_rn(__fmul_rn(q.x - p3.x, q.x - p3.x), __fmul_rn(q.y - p3.y, q.y - p3.y));
        unsigned long long k0 = ((unsigned long long)__float_as_uint(d0) << 32) | (unsigned)j0;
        unsigned long long k1 = ((unsigned long long)__float_as_uint(d1) << 32) | (unsigned)j1;
        unsigned long long k2 = ((unsigned long long)__float_as_uint(d2) << 32) | (unsigned)j2;
        unsigned long long k3 = ((unsigned long long)__float_as_uint(d3) << 32) | (unsigned)j3;
        bm0 = k0 < bm0 ? k0 : bm0;
        bm1 = k1 < bm1 ? k1 : bm1;
        bm2 = k2 < bm2 ? k2 : bm2;
        bm3 = k3 < bm3 ? k3 : bm3;
    }
    unsigned long long bma = bm0 < bm1 ? bm0 : bm1;
    unsigned long long bmb = bm2 < bm3 ? bm2 : bm3;
    unsigned long long bm  = bma < bmb ? bma : bmb;

    // ---- threshold r = 9th smallest of the 32 lane-min keys (upper bound on global 9th key) ----
    unsigned long long KK = bm, r = 0;
#pragma unroll
    for (int rd = 0; rd < 9; ++rd) {
        unsigned long long mn = KK;
#pragma unroll
        for (int s = 1; s <= 16; s <<= 1) {
            unsigned long long o = shfl_xor_u64(mn, s);
            mn = (o < mn) ? o : mn;
        }
        if (KK == mn) KK = ~0ULL;   // owner retires (keys unique)
        r = mn;
    }
    unsigned long long sent = r + 1;  // keys unique: key <= r  <=>  key < sent

    // ---- pass 2: per-lane top-9 insertion, only for keys < sent (rare) ----
    unsigned long long K[9];
#pragma unroll
    for (int m = 0; m < 9; ++m) K[m] = sent;

#pragma unroll 4
    for (int jj = 0; jj < NPTS / 32; ++jj) {
        int j = (jj << 5) + p;
        float2 pt = spos[j];
        float dx = q.x - pt.x;
        float dy = q.y - pt.y;
        float d2 = __fadd_rn(__fmul_rn(dx, dx), __fmul_rn(dy, dy));  // no FMA contraction
        unsigned long long key = ((unsigned long long)__float_as_uint(d2) << 32) | (unsigned)j;
        if (key < K[8]) {
            K[8] = key;
#pragma unroll
            for (int m = 8; m > 0; --m) {
                bool sw = K[m] < K[m - 1];
                unsigned long long a = sw ? K[m - 1] : K[m];
                unsigned long long c = sw ? K[m] : K[m - 1];
                K[m] = a; K[m - 1] = c;
            }
        }
    }

    // ---- 9 extraction rounds: global min over the 32-lane group (>=9 real keys < sent) ----
    int rec = qq;   // inert when correct; keeps downstream in-range if not
#pragma unroll
    for (int rd = 0; rd < 9; ++rd) {
        unsigned long long mn = K[0];
#pragma unroll
        for (int s = 1; s <= 16; s <<= 1) {
            unsigned long long o = shfl_xor_u64(mn, s);
            mn = (o < mn) ? o : mn;
        }
        if (K[0] == mn) {   // this lane owned the min: advance its sorted list
#pragma unroll
            for (int i = 0; i < 8; ++i) K[i] = K[i + 1];
            K[8] = ~0ULL;
        }
        if (rd >= 1 && p == rd - 1) rec = (int)(unsigned)mn;   // rounds 1..8 = the 8 neighbors
    }
    rec &= (NPTS - 1);   // hard-mask to [0,4096): downstream gathers can never fault
    if (p < 8)
        idx[((size_t)b * NPTS + qq) * KNN + p] = rec;
}

// ---------------- gravnet1: identical to round 10 (passed) ----------------
__global__ __launch_bounds__(64) void k_g1(const float* __restrict__ x,
                                           const int* __restrict__ idx,
                                           const float* __restrict__ w1,
                                           const float* __restrict__ b1,
                                           const float* __restrict__ w2,
                                           const float* __restrict__ b2,
                                           float* __restrict__ xcat) {
    __shared__ float sw1[4 * 32], sw2[32 * 32], sb1[32], sb2[32];
    int t = threadIdx.x;
    for (int u = t; u < 128; u += 64) sw1[u] = w1[u];
    for (int u = t; u < 1024; u += 64) sw2[u] = w2[u];
    if (t < 32) { sb1[t] = b1[t]; sb2[t] = b2[t]; }
    __syncthreads();

    int i = blockIdx.x * 64 + t;
    int b = i >> 12;
    int n = i & (NPTS - 1);
    const float* xb = x + (size_t)b * NPTS * FTOT;

    float agg[4] = {0.f, 0.f, 0.f, 0.f};
#pragma unroll
    for (int k = 0; k < KNN; ++k) {
        int nb = idx[(size_t)i * KNN + k];
        const float* f = xb + (size_t)nb * FTOT + 2;
        agg[0] += f[0]; agg[1] += f[1]; agg[2] += f[2]; agg[3] += f[3];
    }
#pragma unroll
    for (int k = 0; k < 4; ++k) agg[k] *= 0.125f;

    float h[32];
#pragma unroll
    for (int o = 0; o < 32; ++o) {
        float a = sb1[o];
#pragma unroll
        for (int k = 0; k < 4; ++k) a += agg[k] * sw1[k * 32 + o];
        h[o] = fmaxf(a, 0.f);
    }
    float* oc = xcat + (size_t)i * 68;
    oc[0] = xb[(size_t)n * FTOT];
    oc[1] = xb[(size_t)n * FTOT + 1];
#pragma unroll
    for (int o = 0; o < 32; ++o) {
        float a = sb2[o];
#pragma unroll
        for (int k = 0; k < 32; ++k) a += h[k] * sw2[k * 32 + o];
        oc[2 + o] = a;
    }
}

// ---------------- gravnet2: identical to round 10 (passed) ----------------
__global__ __launch_bounds__(64) void k_g2(float* __restrict__ xcat,
                                           const int* __restrict__ idx,
                                           const float* __restrict__ w1,
                                           const float* __restrict__ b1,
                                           const float* __restrict__ w2,
                                           const float* __restrict__ b2) {
    __shared__ float sw1[32 * 32], sw2[32 * 32], sb1[32], sb2[32];
    int t = threadIdx.x;
    for (int u = t; u < 1024; u += 64) { sw1[u] = w1[u]; sw2[u] = w2[u]; }
    if (t < 32) { sb1[t] = b1[t]; sb2[t] = b2[t]; }
    __syncthreads();

    int i = blockIdx.x * 64 + t;
    int b = i >> 12;

    float agg[32];
#pragma unroll
    for (int j = 0; j < 32; ++j) agg[j] = 0.f;
#pragma unroll
    for (int k = 0; k < KNN; ++k) {
        int nb = idx[(size_t)i * KNN + k];
        const float* f = xcat + ((size_t)b * NPTS + nb) * 68 + 2;
#pragma unroll
        for (int j = 0; j < 32; ++j) agg[j] += f[j];
    }
#pragma unroll
    for (int j = 0; j < 32; ++j) agg[j] *= 0.125f;

    float h[32];
#pragma unroll
    for (int o = 0; o < 32; ++o) {
        float a = sb1[o];
#pragma unroll
        for (int k = 0; k < 32; ++k) a += agg[k] * sw1[k * 32 + o];
        h[o] = fmaxf(a, 0.f);
    }
    float* oc = xcat + (size_t)i * 68;
    oc[34] = oc[0];
    oc[35] = oc[1];
#pragma unroll
    for (int o = 0; o < 32; ++o) {
        float a = sb2[o];
#pragma unroll
        for (int k = 0; k < 32; ++k) a += h[k] * sw2[k * 32 + o];
        oc[36 + o] = a;
    }
}

// ---------------- fused MLP: identical to round 10 (passed) ----------------
__global__ __launch_bounds__(256) void k_mlp(const float* __restrict__ xcat,
                                             const float* __restrict__ w1, const float* __restrict__ b1,
                                             const float* __restrict__ w2, const float* __restrict__ b2,
                                             const float* __restrict__ w3, const float* __restrict__ b3,
                                             const float* __restrict__ g,  const float* __restrict__ be,
                                             const float* __restrict__ mn, const float* __restrict__ vr,
                                             const float* __restrict__ ow, const float* __restrict__ ob,
                                             float* __restrict__ out) {
    __shared__ float xT[68][36];
    __shared__ float h1T[128][36];
    __shared__ float h2T[64][36];
    int t = threadIdx.x;
    int base = blockIdx.x * 32;

    for (int u = t; u < 32 * 68; u += 256) {
        int p = u / 68, k = u - p * 68;
        xT[k][p] = xcat[(size_t)(base + p) * 68 + k];
    }
    __syncthreads();

    int pq = t & 7;
    int oq = t >> 3;

    {
        const float* bp = b1 + 4 * oq;
        float4 a0 = make_float4(bp[0], bp[0], bp[0], bp[0]);
        float4 a1 = make_float4(bp[1], bp[1], bp[1], bp[1]);
        float4 a2 = make_float4(bp[2], bp[2], bp[2], bp[2]);
        float4 a3 = make_float4(bp[3], bp[3], bp[3], bp[3]);
#pragma unroll 4
        for (int k = 0; k < 68; ++k) {
            float4 xv = *(const float4*)&xT[k][4 * pq];
            const float* wr = w1 + (size_t)k * 128 + 4 * oq;
            float w0v = wr[0], w1v = wr[1], w2v = wr[2], w3v = wr[3];
            a0.x += w0v * xv.x; a0.y += w0v * xv.y; a0.z += w0v * xv.z; a0.w += w0v * xv.w;
            a1.x += w1v * xv.x; a1.y += w1v * xv.y; a1.z += w1v * xv.z; a1.w += w1v * xv.w;
            a2.x += w2v * xv.x; a2.y += w2v * xv.y; a2.z += w2v * xv.z; a2.w += w2v * xv.w;
            a3.x += w3v * xv.x; a3.y += w3v * xv.y; a3.z += w3v * xv.z; a3.w += w3v * xv.w;
        }
        a0.x = fmaxf(a0.x, 0.f); a0.y = fmaxf(a0.y, 0.f); a0.z = fmaxf(a0.z, 0.f); a0.w = fmaxf(a0.w, 0.f);
        a1.x = fmaxf(a1.x, 0.f); a1.y = fmaxf(a1.y, 0.f); a1.z = fmaxf(a1.z, 0.f); a1.w = fmaxf(a1.w, 0.f);
        a2.x = fmaxf(a2.x, 0.f); a2.y = fmaxf(a2.y, 0.f); a2.z = fmaxf(a2.z, 0.f); a2.w = fmaxf(a2.w, 0.f);
        a3.x = fmaxf(a3.x, 0.f); a3.y = fmaxf(a3.y, 0.f); a3.z = fmaxf(a3.z, 0.f); a3.w = fmaxf(a3.w, 0.f);
        *(float4*)&h1T[4 * oq + 0][4 * pq] = a0;
        *(float4*)&h1T[4 * oq + 1][4 * pq] = a1;
        *(float4*)&h1T[4 * oq + 2][4 * pq] = a2;
        *(float4*)&h1T[4 * oq + 3][4 * pq] = a3;
    }
    __syncthreads();

    if (t < 128) {
        const float* bp = b2 + 4 * oq;
        float4 a0 = make_float4(bp[0], bp[0], bp[0], bp[0]);
        float4 a1 = make_float4(bp[1], bp[1], bp[1], bp[1]);
        float4 a2 = make_float4(bp[2], bp[2], bp[2], bp[2]);
        float4 a3 = make_float4(bp[3], bp[3], bp[3], bp[3]);
#pragma unroll 4
        for (int k = 0; k < 128; ++k) {
            float4 xv = *(const float4*)&h1T[k][4 * pq];
            const float* wr = w2 + (size_t)k * 64 + 4 * oq;
            float w0v = wr[0], w1v = wr[1], w2v = wr[2], w3v = wr[3];
            a0.x += w0v * xv.x; a0.y += w0v * xv.y; a0.z += w0v * xv.z; a0.w += w0v * xv.w;
            a1.x += w1v * xv.x; a1.y += w1v * xv.y; a1.z += w1v * xv.z; a1.w += w1v * xv.w;
            a2.x += w2v * xv.x; a2.y += w2v * xv.y; a2.z += w2v * xv.z; a2.w += w2v * xv.w;
            a3.x += w3v * xv.x; a3.y += w3v * xv.y; a3.z += w3v * xv.z; a3.w += w3v * xv.w;
        }
        a0.x = fmaxf(a0.x, 0.f); a0.y = fmaxf(a0.y, 0.f); a0.z = fmaxf(a0.z, 0.f); a0.w = fmaxf(a0.w, 0.f);
        a1.x = fmaxf(a1.x, 0.f); a1.y = fmaxf(a1.y, 0.f); a1.z = fmaxf(a1.z, 0.f); a1.w = fmaxf(a1.w, 0.f);
        a2.x = fmaxf(a2.x, 0.f); a2.y = fmaxf(a2.y, 0.f); a2.z = fmaxf(a2.z, 0.f); a2.w = fmaxf(a2.w, 0.f);
        a3.x = fmaxf(a3.x, 0.f); a3.y = fmaxf(a3.y, 0.f); a3.z = fmaxf(a3.z, 0.f); a3.w = fmaxf(a3.w, 0.f);
        *(float4*)&h2T[4 * oq + 0][4 * pq] = a0;
        *(float4*)&h2T[4 * oq + 1][4 * pq] = a1;
        *(float4*)&h2T[4 * oq + 2][4 * pq] = a2;
        *(float4*)&h2T[4 * oq + 3][4 * pq] = a3;
    }
    __syncthreads();

    if (t < 64) {
        const float* bp = b3 + 4 * oq;
        float4 a0 = make_float4(bp[0], bp[0], bp[0], bp[0]);
        float4 a1 = make_float4(bp[1], bp[1], bp[1], bp[1]);
        float4 a2 = make_float4(bp[2], bp[2], bp[2], bp[2]);
        float4 a3 = make_float4(bp[3], bp[3], bp[3], bp[3]);
#pragma unroll 4
        for (int k = 0; k < 64; ++k) {
            float4 xv = *(const float4*)&h2T[k][4 * pq];
            const float* wr = w3 + (size_t)k * 32 + 4 * oq;
            float w0v = wr[0], w1v = wr[1], w2v = wr[2], w3v = wr[3];
            a0.x += w0v * xv.x; a0.y += w0v * xv.y; a0.z += w0v * xv.z; a0.w += w0v * xv.w;
            a1.x += w1v * xv.x; a1.y += w1v * xv.y; a1.z += w1v * xv.z; a1.w += w1v * xv.w;
            a2.x += w2v * xv.x; a2.y += w2v * xv.y; a2.z += w2v * xv.z; a2.w += w2v * xv.w;
            a3.x += w3v * xv.x; a3.y += w3v * xv.y; a3.z += w3v * xv.z; a3.w += w3v * xv.w;
        }
        a0.x = fmaxf(a0.x, 0.f); a0.y = fmaxf(a0.y, 0.f); a0.z = fmaxf(a0.z, 0.f); a0.w = fmaxf(a0.w, 0.f);
        a1.x = fmaxf(a1.x, 0.f); a1.y = fmaxf(a1.y, 0.f); a1.z = fmaxf(a1.z, 0.f); a1.w = fmaxf(a1.w, 0.f);
        a2.x = fmaxf(a2.x, 0.f); a2.y = fmaxf(a2.y, 0.f); a2.z = fmaxf(a2.z, 0.f); a2.w = fmaxf(a2.w, 0.f);
        a3.x = fmaxf(a3.x, 0.f); a3.y = fmaxf(a3.y, 0.f); a3.z = fmaxf(a3.z, 0.f); a3.w = fmaxf(a3.w, 0.f);
        int c0 = 4 * oq;
        float s0 = g[c0 + 0] * rsqrtf(vr[c0 + 0] + EPSV);
        float s1 = g[c0 + 1] * rsqrtf(vr[c0 + 1] + EPSV);
        float s2 = g[c0 + 2] * rsqrtf(vr[c0 + 2] + EPSV);
        float s3 = g[c0 + 3] * rsqrtf(vr[c0 + 3] + EPSV);
        float w0 = s0 * ow[c0 + 0], w1c = s1 * ow[c0 + 1];
        float w2c = s2 * ow[c0 + 2], w3c = s3 * ow[c0 + 3];
        float tt = (be[c0 + 0] - mn[c0 + 0] * s0) * ow[c0 + 0]
                 + (be[c0 + 1] - mn[c0 + 1] * s1) * ow[c0 + 1]
                 + (be[c0 + 2] - mn[c0 + 2] * s2) * ow[c0 + 2]
                 + (be[c0 + 3] - mn[c0 + 3] * s3) * ow[c0 + 3];
        float4 s;
        s.x = a0.x * w0 + a1.x * w1c + a2.x * w2c + a3.x * w3c;
        s.y = a0.y * w0 + a1.y * w1c + a2.y * w2c + a3.y * w3c;
        s.z = a0.z * w0 + a1.z * w1c + a2.z * w2c + a3.z * w3c;
        s.w = a0.w * w0 + a1.w * w1c + a2.w * w2c + a3.w * w3c;
#pragma unroll
        for (int msk = 8; msk <= 32; msk <<= 1) {
            s.x += __shfl_xor(s.x, msk);
            s.y += __shfl_xor(s.y, msk);
            s.z += __shfl_xor(s.z, msk);
            s.w += __shfl_xor(s.w, msk);
            tt  += __shfl_xor(tt,  msk);
        }
        if (oq == 0) {
            float c = tt + ob[0];
            *(float4*)(out + base + 4 * pq) = make_float4(s.x + c, s.y + c, s.z + c, s.w + c);
        }
    }
}

extern "C" void kernel_launch(void* const* d_in, const int* in_sizes, int n_in,
                              void* d_out, int out_size, void* d_ws, size_t ws_size,
                              hipStream_t stream) {
    const float* inputs    = (const float*)d_in[0];
    const float* bn1_gamma = (const float*)d_in[1];
    const float* bn1_beta  = (const float*)d_in[2];
    const float* bn1_mean  = (const float*)d_in[3];
    const float* bn1_var   = (const float*)d_in[4];
    const float* g1_w1 = (const float*)d_in[5];
    const float* g1_b1 = (const float*)d_in[6];
    const float* g1_w2 = (const float*)d_in[7];
    const float* g1_b2 = (const float*)d_in[8];
    const float* g2_w1 = (const float*)d_in[9];
    const float* g2_b1 = (const float*)d_in[10];
    const float* g2_w2 = (const float*)d_in[11];
    const float* g2_b2 = (const float*)d_in[12];
    const float* d1_w = (const float*)d_in[13];
    const float* d1_b = (const float*)d_in[14];
    const float* d2_w = (const float*)d_in[15];
    const float* d2_b = (const float*)d_in[16];
    const float* d3_w = (const float*)d_in[17];
    const float* d3_b = (const float*)d_in[18];
    const float* bn2_gamma = (const float*)d_in[19];
    const float* bn2_beta  = (const float*)d_in[20];
    const float* bn2_mean  = (const float*)d_in[21];
    const float* bn2_var   = (const float*)d_in[22];
    const float* out_w = (const float*)d_in[23];
    const float* out_b = (const float*)d_in[24];
    float* out = (float*)d_out;

    const size_t BN = (size_t)BTOT * NPTS;
    char* ws = (char*)d_ws;
    size_t off = 0;
    auto alloc = [&](size_t bytes) { char* p = ws + off; off += (bytes + 255) & ~(size_t)255; return p; };
    float*  x    = (float*) alloc(BN * FTOT * sizeof(float));
    float2* pos  = (float2*)alloc(BN * sizeof(float2));
    int*    idx  = (int*)   alloc(BN * KNN  * sizeof(int));
    float*  xcat = (float*) alloc(BN * 68   * sizeof(float));
    (void)ws_size; (void)n_in; (void)in_sizes; (void)out_size;

    k_bn1<<<dim3(64),   dim3(256), 0, stream>>>(inputs, bn1_gamma, bn1_beta, bn1_mean, bn1_var, x, pos);
    k_knn<<<dim3(1024), dim3(512), 0, stream>>>(pos, idx);
    k_g1 <<<dim3(256),  dim3(64),  0, stream>>>(x, idx, g1_w1, g1_b1, g1_w2, g1_b2, xcat);
    k_g2 <<<dim3(256),  dim3(64),  0, stream>>>(xcat, idx, g2_w1, g2_b1, g2_w2, g2_b2);
    k_mlp<<<dim3(512),  dim3(256), 0, stream>>>(xcat, d1_w, d1_b, d2_w, d2_b, d3_w, d3_b,
                                                bn2_gamma, bn2_beta, bn2_mean, bn2_var,
                                                out_w, out_b, out);
}

// Round 13
// 103.962 us; speedup vs baseline: 5.0969x; 1.0521x over previous
//
#include <hip/hip_runtime.h>
#include <hip/hip_bf16.h>

#define BTOT 4
#define NPTS 4096
#define FTOT 6
#define KNN 8
#define EPSV 1e-3f

__device__ __forceinline__ unsigned long long shfl_xor_u64(unsigned long long v, int mask) {
    unsigned lo = (unsigned)v, hi = (unsigned)(v >> 32);
    lo = (unsigned)__shfl_xor((int)lo, mask);
    hi = (unsigned)__shfl_xor((int)hi, mask);
    return ((unsigned long long)hi << 32) | lo;
}

// ---------------- bn1: identical to round 11 (passed) ----------------
__global__ __launch_bounds__(256) void k_bn1(const float* __restrict__ in,
                                             const float* __restrict__ g,
                                             const float* __restrict__ b,
                                             const float* __restrict__ m,
                                             const float* __restrict__ v,
                                             float* __restrict__ x,
                                             float2* __restrict__ pos) {
    int i = blockIdx.x * 256 + threadIdx.x;
    if (i >= BTOT * NPTS) return;
    float o[FTOT];
#pragma unroll
    for (int f = 0; f < FTOT; ++f) {
        float val = in[(size_t)i * FTOT + f];
        o[f] = (val - m[f]) * rsqrtf(v[f] + EPSV) * g[f] + b[f];
        x[(size_t)i * FTOT + f] = o[f];
    }
    pos[i] = make_float2(o[0], o[1]);
}

// ---------------- KNN v6: byte-identical to round 11 (passed). Pure u64 path —
// float-threshold prefilter is PERMANENTLY RETIRED (failed r8 + r12). ----------------
__global__ __launch_bounds__(512) void k_knn(const float2* __restrict__ posg,
                                             int* __restrict__ idx) {
    __shared__ float2 spos[NPTS];  // 32 KB
    int b  = blockIdx.x >> 8;                 // 256 blocks per batch
    int q0 = (blockIdx.x & 255) << 4;         // 16 queries per block
    int t  = threadIdx.x;
    const float2* pb = posg + (size_t)b * NPTS;
    for (int j = t; j < NPTS; j += 512) spos[j] = pb[j];
    __syncthreads();

    int lq = t >> 5;          // local query 0..15
    int p  = t & 31;          // partition lane 0..31
    int qq = q0 + lq;
    float2 q = spos[qq];

    // ---- pass 1: per-lane lexicographic-min u64 key, 4 independent accumulators ----
    unsigned long long bm0 = ~0ULL, bm1 = ~0ULL, bm2 = ~0ULL, bm3 = ~0ULL;
    for (int jj = 0; jj < NPTS / 32; jj += 4) {
        int j0 = ((jj + 0) << 5) + p;
        int j1 = ((jj + 1) << 5) + p;
        int j2 = ((jj + 2) << 5) + p;
        int j3 = ((jj + 3) << 5) + p;
        float2 p0 = spos[j0], p1 = spos[j1], p2 = spos[j2], p3 = spos[j3];
        float d0 = __fadd_rn(__fmul_rn(q.x - p0.x, q.x - p0.x), __fmul_rn(q.y - p0.y, q.y - p0.y));
        float d1 = __fadd_rn(__fmul_rn(q.x - p1.x, q.x - p1.x), __fmul_rn(q.y - p1.y, q.y - p1.y));
        float d2 = __fadd_rn(__fmul_rn(q.x - p2.x, q.x - p2.x), __fmul_rn(q.y - p2.y, q.y - p2.y));
        float d3 = __fadd_rn(__fmul_rn(q.x - p3.x, q.x - p3.x), __fmul_rn(q.y - p3.y, q.y - p3.y));
        unsigned long long k0 = ((unsigned long long)__float_as_uint(d0) << 32) | (unsigned)j0;
        unsigned long long k1 = ((unsigned long long)__float_as_uint(d1) << 32) | (unsigned)j1;
        unsigned long long k2 = ((unsigned long long)__float_as_uint(d2) << 32) | (unsigned)j2;
        unsigned long long k3 = ((unsigned long long)__float_as_uint(d3) << 32) | (unsigned)j3;
        bm0 = k0 < bm0 ? k0 : bm0;
        bm1 = k1 < bm1 ? k1 : bm1;
        bm2 = k2 < bm2 ? k2 : bm2;
        bm3 = k3 < bm3 ? k3 : bm3;
    }
    unsigned long long bma = bm0 < bm1 ? bm0 : bm1;
    unsigned long long bmb = bm2 < bm3 ? bm2 : bm3;
    unsigned long long bm  = bma < bmb ? bma : bmb;

    // ---- threshold r = 9th smallest of the 32 lane-min keys ----
    unsigned long long KK = bm, r = 0;
#pragma unroll
    for (int rd = 0; rd < 9; ++rd) {
        unsigned long long mn = KK;
#pragma unroll
        for (int s = 1; s <= 16; s <<= 1) {
            unsigned long long o = shfl_xor_u64(mn, s);
            mn = (o < mn) ? o : mn;
        }
        if (KK == mn) KK = ~0ULL;   // owner retires (keys unique)
        r = mn;
    }
    unsigned long long sent = r + 1;  // keys unique: key <= r  <=>  key < sent

    // ---- pass 2: per-lane top-9 insertion, only for keys < sent (rare) ----
    unsigned long long K[9];
#pragma unroll
    for (int m = 0; m < 9; ++m) K[m] = sent;

#pragma unroll 4
    for (int jj = 0; jj < NPTS / 32; ++jj) {
        int j = (jj << 5) + p;
        float2 pt = spos[j];
        float dx = q.x - pt.x;
        float dy = q.y - pt.y;
        float d2 = __fadd_rn(__fmul_rn(dx, dx), __fmul_rn(dy, dy));  // no FMA contraction
        unsigned long long key = ((unsigned long long)__float_as_uint(d2) << 32) | (unsigned)j;
        if (key < K[8]) {
            K[8] = key;
#pragma unroll
            for (int m = 8; m > 0; --m) {
                bool sw = K[m] < K[m - 1];
                unsigned long long a = sw ? K[m - 1] : K[m];
                unsigned long long c = sw ? K[m] : K[m - 1];
                K[m] = a; K[m - 1] = c;
            }
        }
    }

    // ---- 9 extraction rounds: global min over the 32-lane group (>=9 real keys < sent) ----
    int rec = qq;   // inert when correct; keeps downstream in-range if not
#pragma unroll
    for (int rd = 0; rd < 9; ++rd) {
        unsigned long long mn = K[0];
#pragma unroll
        for (int s = 1; s <= 16; s <<= 1) {
            unsigned long long o = shfl_xor_u64(mn, s);
            mn = (o < mn) ? o : mn;
        }
        if (K[0] == mn) {   // this lane owned the min: advance its sorted list
#pragma unroll
            for (int i = 0; i < 8; ++i) K[i] = K[i + 1];
            K[8] = ~0ULL;
        }
        if (rd >= 1 && p == rd - 1) rec = (int)(unsigned)mn;   // rounds 1..8 = the 8 neighbors
    }
    rec &= (NPTS - 1);   // hard-mask to [0,4096): downstream gathers can never fault
    if (p < 8)
        idx[((size_t)b * NPTS + qq) * KNN + p] = rec;
}

// ---------------- gravnet1 v2: 4 lanes/point, 64 points/block, 256 blocks ----------------
// lane s of a quad gathers feature s; quad all-gathers via shfl; each lane computes
// its 8 outputs with full k-ascending sums.
__global__ __launch_bounds__(256) void k_g1(const float* __restrict__ x,
                                            const int* __restrict__ idx,
                                            const float* __restrict__ w1,
                                            const float* __restrict__ b1,
                                            const float* __restrict__ w2,
                                            const float* __restrict__ b2,
                                            float* __restrict__ xcat) {
    __shared__ float sw1[4 * 33], sw2[32 * 33], sb1[32], sb2[32];  // +1 pad: conflict-free quad reads
    int t = threadIdx.x;
    if (t < 128) sw1[(t >> 5) * 33 + (t & 31)] = w1[t];
    for (int u = t; u < 1024; u += 256) sw2[(u >> 5) * 33 + (u & 31)] = w2[u];
    if (t < 32) { sb1[t] = b1[t]; sb2[t] = b2[t]; }
    __syncthreads();

    int i = blockIdx.x * 64 + (t >> 2);   // point
    int s = t & 3;                        // sublane
    int qb = (t & 63) & ~3;               // quad base lane within wave
    int b = i >> 12;
    int n = i & (NPTS - 1);
    const float* xb = x + (size_t)b * NPTS * FTOT;

    // gather feature s over 8 neighbors (k ascending)
    float aggs = 0.f;
#pragma unroll
    for (int k = 0; k < KNN; ++k) {
        int nb = idx[(size_t)i * KNN + k];
        aggs += xb[(size_t)nb * FTOT + 2 + s];
    }
    aggs *= 0.125f;

    // all-gather the 4 agg features across the quad
    float af0 = __shfl(aggs, qb + 0);
    float af1 = __shfl(aggs, qb + 1);
    float af2 = __shfl(aggs, qb + 2);
    float af3 = __shfl(aggs, qb + 3);

    // layer 1: lane's 8 outputs, k = 0..3 ascending
    int o0 = 8 * s;
    float h[8];
#pragma unroll
    for (int u = 0; u < 8; ++u) {
        int o = o0 + u;
        float a = af0 * sw1[0 * 33 + o] + af1 * sw1[1 * 33 + o]
                + af2 * sw1[2 * 33 + o] + af3 * sw1[3 * 33 + o];
        h[u] = fmaxf(a + sb1[o], 0.f);
    }

    // all-gather h (32 values) across the quad
    float hf[32];
#pragma unroll
    for (int w = 0; w < 4; ++w)
#pragma unroll
        for (int u = 0; u < 8; ++u)
            hf[8 * w + u] = __shfl(h[u], qb + w);

    // layer 2: lane's 8 outputs, k = 0..31 ascending
    float* oc = xcat + (size_t)i * 68;
    if (s == 0) {
        oc[0] = xb[(size_t)n * FTOT];
        oc[1] = xb[(size_t)n * FTOT + 1];
    }
#pragma unroll
    for (int u = 0; u < 8; ++u) {
        int o = o0 + u;
        float a = 0.f;
#pragma unroll
        for (int k = 0; k < 32; ++k) a += hf[k] * sw2[k * 33 + o];
        oc[2 + o] = a + sb2[o];
    }
}

// ---------------- gravnet2 v2: 4 lanes/point, 64 points/block, 256 blocks ----------------
__global__ __launch_bounds__(256) void k_g2(float* __restrict__ xcat,
                                            const int* __restrict__ idx,
                                            const float* __restrict__ w1,
                                            const float* __restrict__ b1,
                                            const float* __restrict__ w2,
                                            const float* __restrict__ b2) {
    __shared__ float sw1[32 * 33], sw2[32 * 33], sb1[32], sb2[32];
    int t = threadIdx.x;
    for (int u = t; u < 1024; u += 256) {
        sw1[(u >> 5) * 33 + (u & 31)] = w1[u];
        sw2[(u >> 5) * 33 + (u & 31)] = w2[u];
    }
    if (t < 32) { sb1[t] = b1[t]; sb2[t] = b2[t]; }
    __syncthreads();

    int i = blockIdx.x * 64 + (t >> 2);
    int s = t & 3;
    int qb = (t & 63) & ~3;
    int b = i >> 12;

    // gather lane's 8 features (cols 2+8s .. 9+8s) over 8 neighbors (k ascending)
    float agg[8];
#pragma unroll
    for (int u = 0; u < 8; ++u) agg[u] = 0.f;
#pragma unroll
    for (int k = 0; k < KNN; ++k) {
        int nb = idx[(size_t)i * KNN + k];
        const float2* f2 = (const float2*)(xcat + ((size_t)b * NPTS + nb) * 68 + 2 + 8 * s);
#pragma unroll
        for (int w = 0; w < 4; ++w) {
            float2 a = f2[w];
            agg[2 * w]     += a.x;
            agg[2 * w + 1] += a.y;
        }
    }
#pragma unroll
    for (int u = 0; u < 8; ++u) agg[u] *= 0.125f;

    // all-gather agg (32 values) across the quad
    float af[32];
#pragma unroll
    for (int w = 0; w < 4; ++w)
#pragma unroll
        for (int u = 0; u < 8; ++u)
            af[8 * w + u] = __shfl(agg[u], qb + w);

    // layer 1: lane's 8 outputs, k ascending
    int o0 = 8 * s;
    float h[8];
#pragma unroll
    for (int u = 0; u < 8; ++u) {
        int o = o0 + u;
        float a = 0.f;
#pragma unroll
        for (int k = 0; k < 32; ++k) a += af[k] * sw1[k * 33 + o];
        h[u] = fmaxf(a + sb1[o], 0.f);
    }

    // all-gather h
    float hf[32];
#pragma unroll
    for (int w = 0; w < 4; ++w)
#pragma unroll
        for (int u = 0; u < 8; ++u)
            hf[8 * w + u] = __shfl(h[u], qb + w);

    // layer 2: lane's 8 outputs, k ascending
    float* oc = xcat + (size_t)i * 68;
    if (s == 0) {
        oc[34] = oc[0];
        oc[35] = oc[1];
    }
#pragma unroll
    for (int u = 0; u < 8; ++u) {
        int o = o0 + u;
        float a = 0.f;
#pragma unroll
        for (int k = 0; k < 32; ++k) a += hf[k] * sw2[k * 33 + o];
        oc[36 + o] = a + sb2[o];
    }
}

// ---------------- fused MLP: identical to round 11 (passed) ----------------
__global__ __launch_bounds__(256) void k_mlp(const float* __restrict__ xcat,
                                             const float* __restrict__ w1, const float* __restrict__ b1,
                                             const float* __restrict__ w2, const float* __restrict__ b2,
                                             const float* __restrict__ w3, const float* __restrict__ b3,
                                             const float* __restrict__ g,  const float* __restrict__ be,
                                             const float* __restrict__ mn, const float* __restrict__ vr,
                                             const float* __restrict__ ow, const float* __restrict__ ob,
                                             float* __restrict__ out) {
    __shared__ float xT[68][36];
    __shared__ float h1T[128][36];
    __shared__ float h2T[64][36];
    int t = threadIdx.x;
    int base = blockIdx.x * 32;

    for (int u = t; u < 32 * 68; u += 256) {
        int p = u / 68, k = u - p * 68;
        xT[k][p] = xcat[(size_t)(base + p) * 68 + k];
    }
    __syncthreads();

    int pq = t & 7;
    int oq = t >> 3;

    {
        const float* bp = b1 + 4 * oq;
        float4 a0 = make_float4(bp[0], bp[0], bp[0], bp[0]);
        float4 a1 = make_float4(bp[1], bp[1], bp[1], bp[1]);
        float4 a2 = make_float4(bp[2], bp[2], bp[2], bp[2]);
        float4 a3 = make_float4(bp[3], bp[3], bp[3], bp[3]);
#pragma unroll 4
        for (int k = 0; k < 68; ++k) {
            float4 xv = *(const float4*)&xT[k][4 * pq];
            const float* wr = w1 + (size_t)k * 128 + 4 * oq;
            float w0v = wr[0], w1v = wr[1], w2v = wr[2], w3v = wr[3];
            a0.x += w0v * xv.x; a0.y += w0v * xv.y; a0.z += w0v * xv.z; a0.w += w0v * xv.w;
            a1.x += w1v * xv.x; a1.y += w1v * xv.y; a1.z += w1v * xv.z; a1.w += w1v * xv.w;
            a2.x += w2v * xv.x; a2.y += w2v * xv.y; a2.z += w2v * xv.z; a2.w += w2v * xv.w;
            a3.x += w3v * xv.x; a3.y += w3v * xv.y; a3.z += w3v * xv.z; a3.w += w3v * xv.w;
        }
        a0.x = fmaxf(a0.x, 0.f); a0.y = fmaxf(a0.y, 0.f); a0.z = fmaxf(a0.z, 0.f); a0.w = fmaxf(a0.w, 0.f);
        a1.x = fmaxf(a1.x, 0.f); a1.y = fmaxf(a1.y, 0.f); a1.z = fmaxf(a1.z, 0.f); a1.w = fmaxf(a1.w, 0.f);
        a2.x = fmaxf(a2.x, 0.f); a2.y = fmaxf(a2.y, 0.f); a2.z = fmaxf(a2.z, 0.f); a2.w = fmaxf(a2.w, 0.f);
        a3.x = fmaxf(a3.x, 0.f); a3.y = fmaxf(a3.y, 0.f); a3.z = fmaxf(a3.z, 0.f); a3.w = fmaxf(a3.w, 0.f);
        *(float4*)&h1T[4 * oq + 0][4 * pq] = a0;
        *(float4*)&h1T[4 * oq + 1][4 * pq] = a1;
        *(float4*)&h1T[4 * oq + 2][4 * pq] = a2;
        *(float4*)&h1T[4 * oq + 3][4 * pq] = a3;
    }
    __syncthreads();

    if (t < 128) {
        const float* bp = b2 + 4 * oq;
        float4 a0 = make_float4(bp[0], bp[0], bp[0], bp[0]);
        float4 a1 = make_float4(bp[1], bp[1], bp[1], bp[1]);
        float4 a2 = make_float4(bp[2], bp[2], bp[2], bp[2]);
        float4 a3 = make_float4(bp[3], bp[3], bp[3], bp[3]);
#pragma unroll 4
        for (int k = 0; k < 128; ++k) {
            float4 xv = *(const float4*)&h1T[k][4 * pq];
            const float* wr = w2 + (size_t)k * 64 + 4 * oq;
            float w0v = wr[0], w1v = wr[1], w2v = wr[2], w3v = wr[3];
            a0.x += w0v * xv.x; a0.y += w0v * xv.y; a0.z += w0v * xv.z; a0.w += w0v * xv.w;
            a1.x += w1v * xv.x; a1.y += w1v * xv.y; a1.z += w1v * xv.z; a1.w += w1v * xv.w;
            a2.x += w2v * xv.x; a2.y += w2v * xv.y; a2.z += w2v * xv.z; a2.w += w2v * xv.w;
            a3.x += w3v * xv.x; a3.y += w3v * xv.y; a3.z += w3v * xv.z; a3.w += w3v * xv.w;
        }
        a0.x = fmaxf(a0.x, 0.f); a0.y = fmaxf(a0.y, 0.f); a0.z = fmaxf(a0.z, 0.f); a0.w = fmaxf(a0.w, 0.f);
        a1.x = fmaxf(a1.x, 0.f); a1.y = fmaxf(a1.y, 0.f); a1.z = fmaxf(a1.z, 0.f); a1.w = fmaxf(a1.w, 0.f);
        a2.x = fmaxf(a2.x, 0.f); a2.y = fmaxf(a2.y, 0.f); a2.z = fmaxf(a2.z, 0.f); a2.w = fmaxf(a2.w, 0.f);
        a3.x = fmaxf(a3.x, 0.f); a3.y = fmaxf(a3.y, 0.f); a3.z = fmaxf(a3.z, 0.f); a3.w = fmaxf(a3.w, 0.f);
        *(float4*)&h2T[4 * oq + 0][4 * pq] = a0;
        *(float4*)&h2T[4 * oq + 1][4 * pq] = a1;
        *(float4*)&h2T[4 * oq + 2][4 * pq] = a2;
        *(float4*)&h2T[4 * oq + 3][4 * pq] = a3;
    }
    __syncthreads();

    if (t < 64) {
        const float* bp = b3 + 4 * oq;
        float4 a0 = make_float4(bp[0], bp[0], bp[0], bp[0]);
        float4 a1 = make_float4(bp[1], bp[1], bp[1], bp[1]);
        float4 a2 = make_float4(bp[2], bp[2], bp[2], bp[2]);
        float4 a3 = make_float4(bp[3], bp[3], bp[3], bp[3]);
#pragma unroll 4
        for (int k = 0; k < 64; ++k) {
            float4 xv = *(const float4*)&h2T[k][4 * pq];
            const float* wr = w3 + (size_t)k * 32 + 4 * oq;
            float w0v = wr[0], w1v = wr[1], w2v = wr[2], w3v = wr[3];
            a0.x += w0v * xv.x; a0.y += w0v * xv.y; a0.z += w0v * xv.z; a0.w += w0v * xv.w;
            a1.x += w1v * xv.x; a1.y += w1v * xv.y; a1.z += w1v * xv.z; a1.w += w1v * xv.w;
            a2.x += w2v * xv.x; a2.y += w2v * xv.y; a2.z += w2v * xv.z; a2.w += w2v * xv.w;
            a3.x += w3v * xv.x; a3.y += w3v * xv.y; a3.z += w3v * xv.z; a3.w += w3v * xv.w;
        }
        a0.x = fmaxf(a0.x, 0.f); a0.y = fmaxf(a0.y, 0.f); a0.z = fmaxf(a0.z, 0.f); a0.w = fmaxf(a0.w, 0.f);
        a1.x = fmaxf(a1.x, 0.f); a1.y = fmaxf(a1.y, 0.f); a1.z = fmaxf(a1.z, 0.f); a1.w = fmaxf(a1.w, 0.f);
        a2.x = fmaxf(a2.x, 0.f); a2.y = fmaxf(a2.y, 0.f); a2.z = fmaxf(a2.z, 0.f); a2.w = fmaxf(a2.w, 0.f);
        a3.x = fmaxf(a3.x, 0.f); a3.y = fmaxf(a3.y, 0.f); a3.z = fmaxf(a3.z, 0.f); a3.w = fmaxf(a3.w, 0.f);
        int c0 = 4 * oq;
        float s0 = g[c0 + 0] * rsqrtf(vr[c0 + 0] + EPSV);
        float s1 = g[c0 + 1] * rsqrtf(vr[c0 + 1] + EPSV);
        float s2 = g[c0 + 2] * rsqrtf(vr[c0 + 2] + EPSV);
        float s3 = g[c0 + 3] * rsqrtf(vr[c0 + 3] + EPSV);
        float w0 = s0 * ow[c0 + 0], w1c = s1 * ow[c0 + 1];
        float w2c = s2 * ow[c0 + 2], w3c = s3 * ow[c0 + 3];
        float tt = (be[c0 + 0] - mn[c0 + 0] * s0) * ow[c0 + 0]
                 + (be[c0 + 1] - mn[c0 + 1] * s1) * ow[c0 + 1]
                 + (be[c0 + 2] - mn[c0 + 2] * s2) * ow[c0 + 2]
                 + (be[c0 + 3] - mn[c0 + 3] * s3) * ow[c0 + 3];
        float4 s;
        s.x = a0.x * w0 + a1.x * w1c + a2.x * w2c + a3.x * w3c;
        s.y = a0.y * w0 + a1.y * w1c + a2.y * w2c + a3.y * w3c;
        s.z = a0.z * w0 + a1.z * w1c + a2.z * w2c + a3.z * w3c;
        s.w = a0.w * w0 + a1.w * w1c + a2.w * w2c + a3.w * w3c;
#pragma unroll
        for (int msk = 8; msk <= 32; msk <<= 1) {
            s.x += __shfl_xor(s.x, msk);
            s.y += __shfl_xor(s.y, msk);
            s.z += __shfl_xor(s.z, msk);
            s.w += __shfl_xor(s.w, msk);
            tt  += __shfl_xor(tt,  msk);
        }
        if (oq == 0) {
            float c = tt + ob[0];
            *(float4*)(out + base + 4 * pq) = make_float4(s.x + c, s.y + c, s.z + c, s.w + c);
        }
    }
}

extern "C" void kernel_launch(void* const* d_in, const int* in_sizes, int n_in,
                              void* d_out, int out_size, void* d_ws, size_t ws_size,
                              hipStream_t stream) {
    const float* inputs    = (const float*)d_in[0];
    const float* bn1_gamma = (const float*)d_in[1];
    const float* bn1_beta  = (const float*)d_in[2];
    const float* bn1_mean  = (const float*)d_in[3];
    const float* bn1_var   = (const float*)d_in[4];
    const float* g1_w1 = (const float*)d_in[5];
    const float* g1_b1 = (const float*)d_in[6];
    const float* g1_w2 = (const float*)d_in[7];
    const float* g1_b2 = (const float*)d_in[8];
    const float* g2_w1 = (const float*)d_in[9];
    const float* g2_b1 = (const float*)d_in[10];
    const float* g2_w2 = (const float*)d_in[11];
    const float* g2_b2 = (const float*)d_in[12];
    const float* d1_w = (const float*)d_in[13];
    const float* d1_b = (const float*)d_in[14];
    const float* d2_w = (const float*)d_in[15];
    const float* d2_b = (const float*)d_in[16];
    const float* d3_w = (const float*)d_in[17];
    const float* d3_b = (const float*)d_in[18];
    const float* bn2_gamma = (const float*)d_in[19];
    const float* bn2_beta  = (const float*)d_in[20];
    const float* bn2_mean  = (const float*)d_in[21];
    const float* bn2_var   = (const float*)d_in[22];
    const float* out_w = (const float*)d_in[23];
    const float* out_b = (const float*)d_in[24];
    float* out = (float*)d_out;

    const size_t BN = (size_t)BTOT * NPTS;
    char* ws = (char*)d_ws;
    size_t off = 0;
    auto alloc = [&](size_t bytes) { char* p = ws + off; off += (bytes + 255) & ~(size_t)255; return p; };
    float*  x    = (float*) alloc(BN * FTOT * sizeof(float));
    float2* pos  = (float2*)alloc(BN * sizeof(float2));
    int*    idx  = (int*)   alloc(BN * KNN  * sizeof(int));
    float*  xcat = (float*) alloc(BN * 68   * sizeof(float));
    (void)ws_size; (void)n_in; (void)in_sizes; (void)out_size;

    k_bn1<<<dim3(64),   dim3(256), 0, stream>>>(inputs, bn1_gamma, bn1_beta, bn1_mean, bn1_var, x, pos);
    k_knn<<<dim3(1024), dim3(512), 0, stream>>>(pos, idx);
    k_g1 <<<dim3(256),  dim3(256), 0, stream>>>(x, idx, g1_w1, g1_b1, g1_w2, g1_b2, xcat);
    k_g2 <<<dim3(256),  dim3(256), 0, stream>>>(xcat, idx, g2_w1, g2_b1, g2_w2, g2_b2);
    k_mlp<<<dim3(512),  dim3(256), 0, stream>>>(xcat, d1_w, d1_b, d2_w, d2_b, d3_w, d3_b,
                                                bn2_gamma, bn2_beta, bn2_mean, bn2_var,
                                                out_w, out_b, out);
}

// Round 14
// 101.396 us; speedup vs baseline: 5.2259x; 1.0253x over previous
//
#include <hip/hip_runtime.h>
#include <hip/hip_bf16.h>

#define BTOT 4
#define NPTS 4096
#define FTOT 6
#define KNN 8
#define EPSV 1e-3f

// xor-butterfly on u64 via ds_swizzle BitMode (1 LDS-op per 32-bit word).
// Pattern (s<<10)|0x1F == lane' = lane ^ s within each 32-lane half — identical
// to __shfl_xor for s<=16. All call sites are in uniform control flow.
template <int P>
__device__ __forceinline__ unsigned long long swz_xor_u64(unsigned long long v) {
    unsigned lo = (unsigned)v, hi = (unsigned)(v >> 32);
    lo = (unsigned)__builtin_amdgcn_ds_swizzle((int)lo, P);
    hi = (unsigned)__builtin_amdgcn_ds_swizzle((int)hi, P);
    return ((unsigned long long)hi << 32) | lo;
}
#define MERGE_STEP(P) { unsigned long long o_ = swz_xor_u64<P>(mn); mn = (o_ < mn) ? o_ : mn; }
#define MERGE_MIN_U64_32() \
    MERGE_STEP(0x041F) MERGE_STEP(0x081F) MERGE_STEP(0x101F) MERGE_STEP(0x201F) MERGE_STEP(0x401F)

// ---------------- bn1: identical to round 13 (passed) ----------------
__global__ __launch_bounds__(256) void k_bn1(const float* __restrict__ in,
                                             const float* __restrict__ g,
                                             const float* __restrict__ b,
                                             const float* __restrict__ m,
                                             const float* __restrict__ v,
                                             float* __restrict__ x,
                                             float2* __restrict__ pos) {
    int i = blockIdx.x * 256 + threadIdx.x;
    if (i >= BTOT * NPTS) return;
    float o[FTOT];
#pragma unroll
    for (int f = 0; f < FTOT; ++f) {
        float val = in[(size_t)i * FTOT + f];
        o[f] = (val - m[f]) * rsqrtf(v[f] + EPSV) * g[f] + b[f];
        x[(size_t)i * FTOT + f] = o[f];
    }
    pos[i] = make_float2(o[0], o[1]);
}

// ---------------- KNN v6s: round-13 algorithm (pure u64, single-level insert-if),
// merges via ds_swizzle (value-identical to __shfl_xor path) ----------------
__global__ __launch_bounds__(512) void k_knn(const float2* __restrict__ posg,
                                             int* __restrict__ idx) {
    __shared__ float2 spos[NPTS];  // 32 KB
    int b  = blockIdx.x >> 8;                 // 256 blocks per batch
    int q0 = (blockIdx.x & 255) << 4;         // 16 queries per block
    int t  = threadIdx.x;
    const float2* pb = posg + (size_t)b * NPTS;
    for (int j = t; j < NPTS; j += 512) spos[j] = pb[j];
    __syncthreads();

    int lq = t >> 5;          // local query 0..15
    int p  = t & 31;          // partition lane 0..31
    int qq = q0 + lq;
    float2 q = spos[qq];

    // ---- pass 1: per-lane lexicographic-min u64 key, 4 independent accumulators ----
    unsigned long long bm0 = ~0ULL, bm1 = ~0ULL, bm2 = ~0ULL, bm3 = ~0ULL;
    for (int jj = 0; jj < NPTS / 32; jj += 4) {
        int j0 = ((jj + 0) << 5) + p;
        int j1 = ((jj + 1) << 5) + p;
        int j2 = ((jj + 2) << 5) + p;
        int j3 = ((jj + 3) << 5) + p;
        float2 p0 = spos[j0], p1 = spos[j1], p2 = spos[j2], p3 = spos[j3];
        float d0 = __fadd_rn(__fmul_rn(q.x - p0.x, q.x - p0.x), __fmul_rn(q.y - p0.y, q.y - p0.y));
        float d1 = __fadd_rn(__fmul_rn(q.x - p1.x, q.x - p1.x), __fmul_rn(q.y - p1.y, q.y - p1.y));
        float d2 = __fadd_rn(__fmul_rn(q.x - p2.x, q.x - p2.x), __fmul_rn(q.y - p2.y, q.y - p2.y));
        float d3 = __fadd_rn(__fmul_rn(q.x - p3.x, q.x - p3.x), __fmul_rn(q.y - p3.y, q.y - p3.y));
        unsigned long long k0 = ((unsigned long long)__float_as_uint(d0) << 32) | (unsigned)j0;
        unsigned long long k1 = ((unsigned long long)__float_as_uint(d1) << 32) | (unsigned)j1;
        unsigned long long k2 = ((unsigned long long)__float_as_uint(d2) << 32) | (unsigned)j2;
        unsigned long long k3 = ((unsigned long long)__float_as_uint(d3) << 32) | (unsigned)j3;
        bm0 = k0 < bm0 ? k0 : bm0;
        bm1 = k1 < bm1 ? k1 : bm1;
        bm2 = k2 < bm2 ? k2 : bm2;
        bm3 = k3 < bm3 ? k3 : bm3;
    }
    unsigned long long bma = bm0 < bm1 ? bm0 : bm1;
    unsigned long long bmb = bm2 < bm3 ? bm2 : bm3;
    unsigned long long bm  = bma < bmb ? bma : bmb;

    // ---- threshold r = 9th smallest of the 32 lane-min keys ----
    unsigned long long KK = bm, r = 0;
#pragma unroll
    for (int rd = 0; rd < 9; ++rd) {
        unsigned long long mn = KK;
        MERGE_MIN_U64_32()
        if (KK == mn) KK = ~0ULL;   // owner retires (keys unique)
        r = mn;
    }
    unsigned long long sent = r + 1;  // keys unique: key <= r  <=>  key < sent

    // ---- pass 2: per-lane top-9 insertion, single-level if (required structure) ----
    unsigned long long K[9];
#pragma unroll
    for (int m = 0; m < 9; ++m) K[m] = sent;

#pragma unroll 4
    for (int jj = 0; jj < NPTS / 32; ++jj) {
        int j = (jj << 5) + p;
        float2 pt = spos[j];
        float dx = q.x - pt.x;
        float dy = q.y - pt.y;
        float d2 = __fadd_rn(__fmul_rn(dx, dx), __fmul_rn(dy, dy));  // no FMA contraction
        unsigned long long key = ((unsigned long long)__float_as_uint(d2) << 32) | (unsigned)j;
        if (key < K[8]) {
            K[8] = key;
#pragma unroll
            for (int m = 8; m > 0; --m) {
                bool sw = K[m] < K[m - 1];
                unsigned long long a = sw ? K[m - 1] : K[m];
                unsigned long long c = sw ? K[m] : K[m - 1];
                K[m] = a; K[m - 1] = c;
            }
        }
    }

    // ---- 9 extraction rounds: global min over the 32-lane group (>=9 real keys < sent) ----
    int rec = qq;   // inert when correct; keeps downstream in-range if not
#pragma unroll
    for (int rd = 0; rd < 9; ++rd) {
        unsigned long long mn = K[0];
        MERGE_MIN_U64_32()
        if (K[0] == mn) {   // this lane owned the min: advance its sorted list
#pragma unroll
            for (int i = 0; i < 8; ++i) K[i] = K[i + 1];
            K[8] = ~0ULL;
        }
        if (rd >= 1 && p == rd - 1) rec = (int)(unsigned)mn;   // rounds 1..8 = the 8 neighbors
    }
    rec &= (NPTS - 1);   // hard-mask to [0,4096): downstream gathers can never fault
    if (p < 8)
        idx[((size_t)b * NPTS + qq) * KNN + p] = rec;
}

// ---------------- gravnet1 v2: identical to round 13 (passed) ----------------
__global__ __launch_bounds__(256) void k_g1(const float* __restrict__ x,
                                            const int* __restrict__ idx,
                                            const float* __restrict__ w1,
                                            const float* __restrict__ b1,
                                            const float* __restrict__ w2,
                                            const float* __restrict__ b2,
                                            float* __restrict__ xcat) {
    __shared__ float sw1[4 * 33], sw2[32 * 33], sb1[32], sb2[32];
    int t = threadIdx.x;
    if (t < 128) sw1[(t >> 5) * 33 + (t & 31)] = w1[t];
    for (int u = t; u < 1024; u += 256) sw2[(u >> 5) * 33 + (u & 31)] = w2[u];
    if (t < 32) { sb1[t] = b1[t]; sb2[t] = b2[t]; }
    __syncthreads();

    int i = blockIdx.x * 64 + (t >> 2);   // point
    int s = t & 3;                        // sublane
    int qb = (t & 63) & ~3;               // quad base lane within wave
    int b = i >> 12;
    int n = i & (NPTS - 1);
    const float* xb = x + (size_t)b * NPTS * FTOT;

    float aggs = 0.f;
#pragma unroll
    for (int k = 0; k < KNN; ++k) {
        int nb = idx[(size_t)i * KNN + k];
        aggs += xb[(size_t)nb * FTOT + 2 + s];
    }
    aggs *= 0.125f;

    float af0 = __shfl(aggs, qb + 0);
    float af1 = __shfl(aggs, qb + 1);
    float af2 = __shfl(aggs, qb + 2);
    float af3 = __shfl(aggs, qb + 3);

    int o0 = 8 * s;
    float h[8];
#pragma unroll
    for (int u = 0; u < 8; ++u) {
        int o = o0 + u;
        float a = af0 * sw1[0 * 33 + o] + af1 * sw1[1 * 33 + o]
                + af2 * sw1[2 * 33 + o] + af3 * sw1[3 * 33 + o];
        h[u] = fmaxf(a + sb1[o], 0.f);
    }

    float hf[32];
#pragma unroll
    for (int w = 0; w < 4; ++w)
#pragma unroll
        for (int u = 0; u < 8; ++u)
            hf[8 * w + u] = __shfl(h[u], qb + w);

    float* oc = xcat + (size_t)i * 68;
    if (s == 0) {
        oc[0] = xb[(size_t)n * FTOT];
        oc[1] = xb[(size_t)n * FTOT + 1];
    }
#pragma unroll
    for (int u = 0; u < 8; ++u) {
        int o = o0 + u;
        float a = 0.f;
#pragma unroll
        for (int k = 0; k < 32; ++k) a += hf[k] * sw2[k * 33 + o];
        oc[2 + o] = a + sb2[o];
    }
}

// ---------------- gravnet2 v2: identical to round 13 (passed) ----------------
__global__ __launch_bounds__(256) void k_g2(float* __restrict__ xcat,
                                            const int* __restrict__ idx,
                                            const float* __restrict__ w1,
                                            const float* __restrict__ b1,
                                            const float* __restrict__ w2,
                                            const float* __restrict__ b2) {
    __shared__ float sw1[32 * 33], sw2[32 * 33], sb1[32], sb2[32];
    int t = threadIdx.x;
    for (int u = t; u < 1024; u += 256) {
        sw1[(u >> 5) * 33 + (u & 31)] = w1[u];
        sw2[(u >> 5) * 33 + (u & 31)] = w2[u];
    }
    if (t < 32) { sb1[t] = b1[t]; sb2[t] = b2[t]; }
    __syncthreads();

    int i = blockIdx.x * 64 + (t >> 2);
    int s = t & 3;
    int qb = (t & 63) & ~3;
    int b = i >> 12;

    float agg[8];
#pragma unroll
    for (int u = 0; u < 8; ++u) agg[u] = 0.f;
#pragma unroll
    for (int k = 0; k < KNN; ++k) {
        int nb = idx[(size_t)i * KNN + k];
        const float2* f2 = (const float2*)(xcat + ((size_t)b * NPTS + nb) * 68 + 2 + 8 * s);
#pragma unroll
        for (int w = 0; w < 4; ++w) {
            float2 a = f2[w];
            agg[2 * w]     += a.x;
            agg[2 * w + 1] += a.y;
        }
    }
#pragma unroll
    for (int u = 0; u < 8; ++u) agg[u] *= 0.125f;

    float af[32];
#pragma unroll
    for (int w = 0; w < 4; ++w)
#pragma unroll
        for (int u = 0; u < 8; ++u)
            af[8 * w + u] = __shfl(agg[u], qb + w);

    int o0 = 8 * s;
    float h[8];
#pragma unroll
    for (int u = 0; u < 8; ++u) {
        int o = o0 + u;
        float a = 0.f;
#pragma unroll
        for (int k = 0; k < 32; ++k) a += af[k] * sw1[k * 33 + o];
        h[u] = fmaxf(a + sb1[o], 0.f);
    }

    float hf[32];
#pragma unroll
    for (int w = 0; w < 4; ++w)
#pragma unroll
        for (int u = 0; u < 8; ++u)
            hf[8 * w + u] = __shfl(h[u], qb + w);

    float* oc = xcat + (size_t)i * 68;
    if (s == 0) {
        oc[34] = oc[0];
        oc[35] = oc[1];
    }
#pragma unroll
    for (int u = 0; u < 8; ++u) {
        int o = o0 + u;
        float a = 0.f;
#pragma unroll
        for (int k = 0; k < 32; ++k) a += hf[k] * sw2[k * 33 + o];
        oc[36 + o] = a + sb2[o];
    }
}

// ---------------- fused MLP: round-13 structure + float4 weight/bias loads
// (value-identical: same bits, same FMA order; knn aborts exonerated global float4) ----------------
__global__ __launch_bounds__(256) void k_mlp(const float* __restrict__ xcat,
                                             const float* __restrict__ w1, const float* __restrict__ b1,
                                             const float* __restrict__ w2, const float* __restrict__ b2,
                                             const float* __restrict__ w3, const float* __restrict__ b3,
                                             const float* __restrict__ g,  const float* __restrict__ be,
                                             const float* __restrict__ mn, const float* __restrict__ vr,
                                             const float* __restrict__ ow, const float* __restrict__ ob,
                                             float* __restrict__ out) {
    __shared__ float xT[68][36];
    __shared__ float h1T[128][36];
    __shared__ float h2T[64][36];
    int t = threadIdx.x;
    int base = blockIdx.x * 32;

    for (int u = t; u < 32 * 68; u += 256) {
        int p = u / 68, k = u - p * 68;
        xT[k][p] = xcat[(size_t)(base + p) * 68 + k];
    }
    __syncthreads();

    int pq = t & 7;
    int oq = t >> 3;

    {
        float4 bb = *(const float4*)(b1 + 4 * oq);
        float4 a0 = make_float4(bb.x, bb.x, bb.x, bb.x);
        float4 a1 = make_float4(bb.y, bb.y, bb.y, bb.y);
        float4 a2 = make_float4(bb.z, bb.z, bb.z, bb.z);
        float4 a3 = make_float4(bb.w, bb.w, bb.w, bb.w);
#pragma unroll 4
        for (int k = 0; k < 68; ++k) {
            float4 xv = *(const float4*)&xT[k][4 * pq];
            float4 wv = *(const float4*)(w1 + (size_t)k * 128 + 4 * oq);
            a0.x += wv.x * xv.x; a0.y += wv.x * xv.y; a0.z += wv.x * xv.z; a0.w += wv.x * xv.w;
            a1.x += wv.y * xv.x; a1.y += wv.y * xv.y; a1.z += wv.y * xv.z; a1.w += wv.y * xv.w;
            a2.x += wv.z * xv.x; a2.y += wv.z * xv.y; a2.z += wv.z * xv.z; a2.w += wv.z * xv.w;
            a3.x += wv.w * xv.x; a3.y += wv.w * xv.y; a3.z += wv.w * xv.z; a3.w += wv.w * xv.w;
        }
        a0.x = fmaxf(a0.x, 0.f); a0.y = fmaxf(a0.y, 0.f); a0.z = fmaxf(a0.z, 0.f); a0.w = fmaxf(a0.w, 0.f);
        a1.x = fmaxf(a1.x, 0.f); a1.y = fmaxf(a1.y, 0.f); a1.z = fmaxf(a1.z, 0.f); a1.w = fmaxf(a1.w, 0.f);
        a2.x = fmaxf(a2.x, 0.f); a2.y = fmaxf(a2.y, 0.f); a2.z = fmaxf(a2.z, 0.f); a2.w = fmaxf(a2.w, 0.f);
        a3.x = fmaxf(a3.x, 0.f); a3.y = fmaxf(a3.y, 0.f); a3.z = fmaxf(a3.z, 0.f); a3.w = fmaxf(a3.w, 0.f);
        *(float4*)&h1T[4 * oq + 0][4 * pq] = a0;
        *(float4*)&h1T[4 * oq + 1][4 * pq] = a1;
        *(float4*)&h1T[4 * oq + 2][4 * pq] = a2;
        *(float4*)&h1T[4 * oq + 3][4 * pq] = a3;
    }
    __syncthreads();

    if (t < 128) {
        float4 bb = *(const float4*)(b2 + 4 * oq);
        float4 a0 = make_float4(bb.x, bb.x, bb.x, bb.x);
        float4 a1 = make_float4(bb.y, bb.y, bb.y, bb.y);
        float4 a2 = make_float4(bb.z, bb.z, bb.z, bb.z);
        float4 a3 = make_float4(bb.w, bb.w, bb.w, bb.w);
#pragma unroll 4
        for (int k = 0; k < 128; ++k) {
            float4 xv = *(const float4*)&h1T[k][4 * pq];
            float4 wv = *(const float4*)(w2 + (size_t)k * 64 + 4 * oq);
            a0.x += wv.x * xv.x; a0.y += wv.x * xv.y; a0.z += wv.x * xv.z; a0.w += wv.x * xv.w;
            a1.x += wv.y * xv.x; a1.y += wv.y * xv.y; a1.z += wv.y * xv.z; a1.w += wv.y * xv.w;
            a2.x += wv.z * xv.x; a2.y += wv.z * xv.y; a2.z += wv.z * xv.z; a2.w += wv.z * xv.w;
            a3.x += wv.w * xv.x; a3.y += wv.w * xv.y; a3.z += wv.w * xv.z; a3.w += wv.w * xv.w;
        }
        a0.x = fmaxf(a0.x, 0.f); a0.y = fmaxf(a0.y, 0.f); a0.z = fmaxf(a0.z, 0.f); a0.w = fmaxf(a0.w, 0.f);
        a1.x = fmaxf(a1.x, 0.f); a1.y = fmaxf(a1.y, 0.f); a1.z = fmaxf(a1.z, 0.f); a1.w = fmaxf(a1.w, 0.f);
        a2.x = fmaxf(a2.x, 0.f); a2.y = fmaxf(a2.y, 0.f); a2.z = fmaxf(a2.z, 0.f); a2.w = fmaxf(a2.w, 0.f);
        a3.x = fmaxf(a3.x, 0.f); a3.y = fmaxf(a3.y, 0.f); a3.z = fmaxf(a3.z, 0.f); a3.w = fmaxf(a3.w, 0.f);
        *(float4*)&h2T[4 * oq + 0][4 * pq] = a0;
        *(float4*)&h2T[4 * oq + 1][4 * pq] = a1;
        *(float4*)&h2T[4 * oq + 2][4 * pq] = a2;
        *(float4*)&h2T[4 * oq + 3][4 * pq] = a3;
    }
    __syncthreads();

    if (t < 64) {
        float4 bb = *(const float4*)(b3 + 4 * oq);
        float4 a0 = make_float4(bb.x, bb.x, bb.x, bb.x);
        float4 a1 = make_float4(bb.y, bb.y, bb.y, bb.y);
        float4 a2 = make_float4(bb.z, bb.z, bb.z, bb.z);
        float4 a3 = make_float4(bb.w, bb.w, bb.w, bb.w);
#pragma unroll 4
        for (int k = 0; k < 64; ++k) {
            float4 xv = *(const float4*)&h2T[k][4 * pq];
            float4 wv = *(const float4*)(w3 + (size_t)k * 32 + 4 * oq);
            a0.x += wv.x * xv.x; a0.y += wv.x * xv.y; a0.z += wv.x * xv.z; a0.w += wv.x * xv.w;
            a1.x += wv.y * xv.x; a1.y += wv.y * xv.y; a1.z += wv.y * xv.z; a1.w += wv.y * xv.w;
            a2.x += wv.z * xv.x; a2.y += wv.z * xv.y; a2.z += wv.z * xv.z; a2.w += wv.z * xv.w;
            a3.x += wv.w * xv.x; a3.y += wv.w * xv.y; a3.z += wv.w * xv.z; a3.w += wv.w * xv.w;
        }
        a0.x = fmaxf(a0.x, 0.f); a0.y = fmaxf(a0.y, 0.f); a0.z = fmaxf(a0.z, 0.f); a0.w = fmaxf(a0.w, 0.f);
        a1.x = fmaxf(a1.x, 0.f); a1.y = fmaxf(a1.y, 0.f); a1.z = fmaxf(a1.z, 0.f); a1.w = fmaxf(a1.w, 0.f);
        a2.x = fmaxf(a2.x, 0.f); a2.y = fmaxf(a2.y, 0.f); a2.z = fmaxf(a2.z, 0.f); a2.w = fmaxf(a2.w, 0.f);
        a3.x = fmaxf(a3.x, 0.f); a3.y = fmaxf(a3.y, 0.f); a3.z = fmaxf(a3.z, 0.f); a3.w = fmaxf(a3.w, 0.f);
        int c0 = 4 * oq;
        float s0 = g[c0 + 0] * rsqrtf(vr[c0 + 0] + EPSV);
        float s1 = g[c0 + 1] * rsqrtf(vr[c0 + 1] + EPSV);
        float s2 = g[c0 + 2] * rsqrtf(vr[c0 + 2] + EPSV);
        float s3 = g[c0 + 3] * rsqrtf(vr[c0 + 3] + EPSV);
        float w0 = s0 * ow[c0 + 0], w1c = s1 * ow[c0 + 1];
        float w2c = s2 * ow[c0 + 2], w3c = s3 * ow[c0 + 3];
        float tt = (be[c0 + 0] - mn[c0 + 0] * s0) * ow[c0 + 0]
                 + (be[c0 + 1] - mn[c0 + 1] * s1) * ow[c0 + 1]
                 + (be[c0 + 2] - mn[c0 + 2] * s2) * ow[c0 + 2]
                 + (be[c0 + 3] - mn[c0 + 3] * s3) * ow[c0 + 3];
        float4 s;
        s.x = a0.x * w0 + a1.x * w1c + a2.x * w2c + a3.x * w3c;
        s.y = a0.y * w0 + a1.y * w1c + a2.y * w2c + a3.y * w3c;
        s.z = a0.z * w0 + a1.z * w1c + a2.z * w2c + a3.z * w3c;
        s.w = a0.w * w0 + a1.w * w1c + a2.w * w2c + a3.w * w3c;
#pragma unroll
        for (int msk = 8; msk <= 32; msk <<= 1) {
            s.x += __shfl_xor(s.x, msk);
            s.y += __shfl_xor(s.y, msk);
            s.z += __shfl_xor(s.z, msk);
            s.w += __shfl_xor(s.w, msk);
            tt  += __shfl_xor(tt,  msk);
        }
        if (oq == 0) {
            float c = tt + ob[0];
            *(float4*)(out + base + 4 * pq) = make_float4(s.x + c, s.y + c, s.z + c, s.w + c);
        }
    }
}

extern "C" void kernel_launch(void* const* d_in, const int* in_sizes, int n_in,
                              void* d_out, int out_size, void* d_ws, size_t ws_size,
                              hipStream_t stream) {
    const float* inputs    = (const float*)d_in[0];
    const float* bn1_gamma = (const float*)d_in[1];
    const float* bn1_beta  = (const float*)d_in[2];
    const float* bn1_mean  = (const float*)d_in[3];
    const float* bn1_var   = (const float*)d_in[4];
    const float* g1_w1 = (const float*)d_in[5];
    const float* g1_b1 = (const float*)d_in[6];
    const float* g1_w2 = (const float*)d_in[7];
    const float* g1_b2 = (const float*)d_in[8];
    const float* g2_w1 = (const float*)d_in[9];
    const float* g2_b1 = (const float*)d_in[10];
    const float* g2_w2 = (const float*)d_in[11];
    const float* g2_b2 = (const float*)d_in[12];
    const float* d1_w = (const float*)d_in[13];
    const float* d1_b = (const float*)d_in[14];
    const float* d2_w = (const float*)d_in[15];
    const float* d2_b = (const float*)d_in[16];
    const float* d3_w = (const float*)d_in[17];
    const float* d3_b = (const float*)d_in[18];
    const float* bn2_gamma = (const float*)d_in[19];
    const float* bn2_beta  = (const float*)d_in[20];
    const float* bn2_mean  = (const float*)d_in[21];
    const float* bn2_var   = (const float*)d_in[22];
    const float* out_w = (const float*)d_in[23];
    const float* out_b = (const float*)d_in[24];
    float* out = (float*)d_out;

    const size_t BN = (size_t)BTOT * NPTS;
    char* ws = (char*)d_ws;
    size_t off = 0;
    auto alloc = [&](size_t bytes) { char* p = ws + off; off += (bytes + 255) & ~(size_t)255; return p; };
    float*  x    = (float*) alloc(BN * FTOT * sizeof(float));
    float2* pos  = (float2*)alloc(BN * sizeof(float2));
    int*    idx  = (int*)   alloc(BN * KNN  * sizeof(int));
    float*  xcat = (float*) alloc(BN * 68   * sizeof(float));
    (void)ws_size; (void)n_in; (void)in_sizes; (void)out_size;

    k_bn1<<<dim3(64),   dim3(256), 0, stream>>>(inputs, bn1_gamma, bn1_beta, bn1_mean, bn1_var, x, pos);
    k_knn<<<dim3(1024), dim3(512), 0, stream>>>(pos, idx);
    k_g1 <<<dim3(256),  dim3(256), 0, stream>>>(x, idx, g1_w1, g1_b1, g1_w2, g1_b2, xcat);
    k_g2 <<<dim3(256),  dim3(256), 0, stream>>>(xcat, idx, g2_w1, g2_b1, g2_w2, g2_b2);
    k_mlp<<<dim3(512),  dim3(256), 0, stream>>>(xcat, d1_w, d1_b, d2_w, d2_b, d3_w, d3_b,
                                                bn2_gamma, bn2_beta, bn2_mean, bn2_var,
                                                out_w, out_b, out);
}

// Round 16
// 97.097 us; speedup vs baseline: 5.4573x; 1.0443x over previous
//
#include <hip/hip_runtime.h>
#include <hip/hip_bf16.h>

#define BTOT 4
#define NPTS 4096
#define FTOT 6
#define KNN 8
#define EPSV 1e-3f

// xor-butterfly on u64 via ds_swizzle BitMode (1 LDS-op per 32-bit word).
template <int P>
__device__ __forceinline__ unsigned long long swz_xor_u64(unsigned long long v) {
    unsigned lo = (unsigned)v, hi = (unsigned)(v >> 32);
    lo = (unsigned)__builtin_amdgcn_ds_swizzle((int)lo, P);
    hi = (unsigned)__builtin_amdgcn_ds_swizzle((int)hi, P);
    return ((unsigned long long)hi << 32) | lo;
}
#define MERGE_STEP(P) { unsigned long long o_ = swz_xor_u64<P>(mn); mn = (o_ < mn) ? o_ : mn; }
#define MERGE_MIN_U64_32() \
    MERGE_STEP(0x041F) MERGE_STEP(0x081F) MERGE_STEP(0x101F) MERGE_STEP(0x201F) MERGE_STEP(0x401F)

// ---------------- bn1: identical to round 14 (passed) ----------------
__global__ __launch_bounds__(256) void k_bn1(const float* __restrict__ in,
                                             const float* __restrict__ g,
                                             const float* __restrict__ b,
                                             const float* __restrict__ m,
                                             const float* __restrict__ v,
                                             float* __restrict__ x,
                                             float2* __restrict__ pos) {
    int i = blockIdx.x * 256 + threadIdx.x;
    if (i >= BTOT * NPTS) return;
    float o[FTOT];
#pragma unroll
    for (int f = 0; f < FTOT; ++f) {
        float val = in[(size_t)i * FTOT + f];
        o[f] = (val - m[f]) * rsqrtf(v[f] + EPSV) * g[f] + b[f];
        x[(size_t)i * FTOT + f] = o[f];
    }
    pos[i] = make_float2(o[0], o[1]);
}

// ---------------- KNN v6s: byte-identical to round 14 (passed). SELECTION MATH FROZEN:
// u64-key pass-1 + u64 threshold + single-level u64 pass-2. Float-threshold variants
// failed 4x (r4-8, r12, r15) — permanently retired. ----------------
__global__ __launch_bounds__(512) void k_knn(const float2* __restrict__ posg,
                                             int* __restrict__ idx) {
    __shared__ float2 spos[NPTS];  // 32 KB
    int b  = blockIdx.x >> 8;                 // 256 blocks per batch
    int q0 = (blockIdx.x & 255) << 4;         // 16 queries per block
    int t  = threadIdx.x;
    const float2* pb = posg + (size_t)b * NPTS;
    for (int j = t; j < NPTS; j += 512) spos[j] = pb[j];
    __syncthreads();

    int lq = t >> 5;          // local query 0..15
    int p  = t & 31;          // partition lane 0..31
    int qq = q0 + lq;
    float2 q = spos[qq];

    // ---- pass 1: per-lane lexicographic-min u64 key, 4 independent accumulators ----
    unsigned long long bm0 = ~0ULL, bm1 = ~0ULL, bm2 = ~0ULL, bm3 = ~0ULL;
    for (int jj = 0; jj < NPTS / 32; jj += 4) {
        int j0 = ((jj + 0) << 5) + p;
        int j1 = ((jj + 1) << 5) + p;
        int j2 = ((jj + 2) << 5) + p;
        int j3 = ((jj + 3) << 5) + p;
        float2 p0 = spos[j0], p1 = spos[j1], p2 = spos[j2], p3 = spos[j3];
        float d0 = __fadd_rn(__fmul_rn(q.x - p0.x, q.x - p0.x), __fmul_rn(q.y - p0.y, q.y - p0.y));
        float d1 = __fadd_rn(__fmul_rn(q.x - p1.x, q.x - p1.x), __fmul_rn(q.y - p1.y, q.y - p1.y));
        float d2 = __fadd_rn(__fmul_rn(q.x - p2.x, q.x - p2.x), __fmul_rn(q.y - p2.y, q.y - p2.y));
        float d3 = __fadd_rn(__fmul_rn(q.x - p3.x, q.x - p3.x), __fmul_rn(q.y - p3.y, q.y - p3.y));
        unsigned long long k0 = ((unsigned long long)__float_as_uint(d0) << 32) | (unsigned)j0;
        unsigned long long k1 = ((unsigned long long)__float_as_uint(d1) << 32) | (unsigned)j1;
        unsigned long long k2 = ((unsigned long long)__float_as_uint(d2) << 32) | (unsigned)j2;
        unsigned long long k3 = ((unsigned long long)__float_as_uint(d3) << 32) | (unsigned)j3;
        bm0 = k0 < bm0 ? k0 : bm0;
        bm1 = k1 < bm1 ? k1 : bm1;
        bm2 = k2 < bm2 ? k2 : bm2;
        bm3 = k3 < bm3 ? k3 : bm3;
    }
    unsigned long long bma = bm0 < bm1 ? bm0 : bm1;
    unsigned long long bmb = bm2 < bm3 ? bm2 : bm3;
    unsigned long long bm  = bma < bmb ? bma : bmb;

    // ---- threshold r = 9th smallest of the 32 lane-min keys ----
    unsigned long long KK = bm, r = 0;
#pragma unroll
    for (int rd = 0; rd < 9; ++rd) {
        unsigned long long mn = KK;
        MERGE_MIN_U64_32()
        if (KK == mn) KK = ~0ULL;   // owner retires (keys unique)
        r = mn;
    }
    unsigned long long sent = r + 1;  // keys unique: key <= r  <=>  key < sent

    // ---- pass 2: per-lane top-9 insertion, single-level if (required structure) ----
    unsigned long long K[9];
#pragma unroll
    for (int m = 0; m < 9; ++m) K[m] = sent;

#pragma unroll 4
    for (int jj = 0; jj < NPTS / 32; ++jj) {
        int j = (jj << 5) + p;
        float2 pt = spos[j];
        float dx = q.x - pt.x;
        float dy = q.y - pt.y;
        float d2 = __fadd_rn(__fmul_rn(dx, dx), __fmul_rn(dy, dy));  // no FMA contraction
        unsigned long long key = ((unsigned long long)__float_as_uint(d2) << 32) | (unsigned)j;
        if (key < K[8]) {
            K[8] = key;
#pragma unroll
            for (int m = 8; m > 0; --m) {
                bool sw = K[m] < K[m - 1];
                unsigned long long a = sw ? K[m - 1] : K[m];
                unsigned long long c = sw ? K[m] : K[m - 1];
                K[m] = a; K[m - 1] = c;
            }
        }
    }

    // ---- 9 extraction rounds: global min over the 32-lane group (>=9 real keys < sent) ----
    int rec = qq;   // inert when correct; keeps downstream in-range if not
#pragma unroll
    for (int rd = 0; rd < 9; ++rd) {
        unsigned long long mn = K[0];
        MERGE_MIN_U64_32()
        if (K[0] == mn) {   // this lane owned the min: advance its sorted list
#pragma unroll
            for (int i = 0; i < 8; ++i) K[i] = K[i + 1];
            K[8] = ~0ULL;
        }
        if (rd >= 1 && p == rd - 1) rec = (int)(unsigned)mn;   // rounds 1..8 = the 8 neighbors
    }
    rec &= (NPTS - 1);   // hard-mask to [0,4096): downstream gathers can never fault
    if (p < 8)
        idx[((size_t)b * NPTS + qq) * KNN + p] = rec;
}

// ---------------- gravnet1 v2: identical to round 14 (passed) ----------------
__global__ __launch_bounds__(256) void k_g1(const float* __restrict__ x,
                                            const int* __restrict__ idx,
                                            const float* __restrict__ w1,
                                            const float* __restrict__ b1,
                                            const float* __restrict__ w2,
                                            const float* __restrict__ b2,
                                            float* __restrict__ xcat) {
    __shared__ float sw1[4 * 33], sw2[32 * 33], sb1[32], sb2[32];
    int t = threadIdx.x;
    if (t < 128) sw1[(t >> 5) * 33 + (t & 31)] = w1[t];
    for (int u = t; u < 1024; u += 256) sw2[(u >> 5) * 33 + (u & 31)] = w2[u];
    if (t < 32) { sb1[t] = b1[t]; sb2[t] = b2[t]; }
    __syncthreads();

    int i = blockIdx.x * 64 + (t >> 2);   // point
    int s = t & 3;                        // sublane
    int qb = (t & 63) & ~3;               // quad base lane within wave
    int b = i >> 12;
    int n = i & (NPTS - 1);
    const float* xb = x + (size_t)b * NPTS * FTOT;

    float aggs = 0.f;
#pragma unroll
    for (int k = 0; k < KNN; ++k) {
        int nb = idx[(size_t)i * KNN + k];
        aggs += xb[(size_t)nb * FTOT + 2 + s];
    }
    aggs *= 0.125f;

    float af0 = __shfl(aggs, qb + 0);
    float af1 = __shfl(aggs, qb + 1);
    float af2 = __shfl(aggs, qb + 2);
    float af3 = __shfl(aggs, qb + 3);

    int o0 = 8 * s;
    float h[8];
#pragma unroll
    for (int u = 0; u < 8; ++u) {
        int o = o0 + u;
        float a = af0 * sw1[0 * 33 + o] + af1 * sw1[1 * 33 + o]
                + af2 * sw1[2 * 33 + o] + af3 * sw1[3 * 33 + o];
        h[u] = fmaxf(a + sb1[o], 0.f);
    }

    float hf[32];
#pragma unroll
    for (int w = 0; w < 4; ++w)
#pragma unroll
        for (int u = 0; u < 8; ++u)
            hf[8 * w + u] = __shfl(h[u], qb + w);

    float* oc = xcat + (size_t)i * 68;
    if (s == 0) {
        oc[0] = xb[(size_t)n * FTOT];
        oc[1] = xb[(size_t)n * FTOT + 1];
    }
#pragma unroll
    for (int u = 0; u < 8; ++u) {
        int o = o0 + u;
        float a = 0.f;
#pragma unroll
        for (int k = 0; k < 32; ++k) a += hf[k] * sw2[k * 33 + o];
        oc[2 + o] = a + sb2[o];
    }
}

// ---------------- FUSED g2 + mlp: 32 points/block, 512 blocks ----------------
// Phase A (t<128): round-14 g2 body (4 lanes/point), outputs -> xT rows 34..67 (LDS only;
// xcat cols [34,68) are never written/read in global anymore).
// Phases d1/d2/d3/out: byte-identical to round-14 k_mlp.
__global__ __launch_bounds__(256) void k_g2m(const float* __restrict__ xcat,
                                             const int* __restrict__ idx,
                                             const float* __restrict__ gw1, const float* __restrict__ gb1,
                                             const float* __restrict__ gw2, const float* __restrict__ gb2,
                                             const float* __restrict__ w1, const float* __restrict__ b1,
                                             const float* __restrict__ w2, const float* __restrict__ b2,
                                             const float* __restrict__ w3, const float* __restrict__ b3,
                                             const float* __restrict__ g,  const float* __restrict__ be,
                                             const float* __restrict__ mn, const float* __restrict__ vr,
                                             const float* __restrict__ ow, const float* __restrict__ ob,
                                             float* __restrict__ out) {
    __shared__ float sw1[32 * 33], sw2[32 * 33], sb1[32], sb2[32];
    __shared__ float xT[68][36];
    __shared__ float h1T[128][36];
    __shared__ float h2T[64][36];
    int t = threadIdx.x;
    int base = blockIdx.x * 32;

    // stage g2 weights + x1 region (rows 0..33 from g1's global output)
    for (int u = t; u < 1024; u += 256) {
        sw1[(u >> 5) * 33 + (u & 31)] = gw1[u];
        sw2[(u >> 5) * 33 + (u & 31)] = gw2[u];
    }
    if (t < 32) { sb1[t] = gb1[t]; sb2[t] = gb2[t]; }
    for (int u = t; u < 32 * 34; u += 256) {
        int p = u / 34, k = u - p * 34;
        xT[k][p] = xcat[(size_t)(base + p) * 68 + k];
    }
    __syncthreads();

    // ---- phase A: g2 for this block's 32 points (threads 0..127 = 4 lanes x 32 points) ----
    if (t < 128) {
        int pt = t >> 2;                    // local point 0..31
        int s  = t & 3;                     // sublane
        int qb = (t & 63) & ~3;             // quad base lane within wave
        int i  = base + pt;
        int b  = i >> 12;

        float agg[8];
#pragma unroll
        for (int u = 0; u < 8; ++u) agg[u] = 0.f;
#pragma unroll
        for (int k = 0; k < KNN; ++k) {
            int nb = idx[(size_t)i * KNN + k];
            const float2* f2 = (const float2*)(xcat + ((size_t)b * NPTS + nb) * 68 + 2 + 8 * s);
#pragma unroll
            for (int w = 0; w < 4; ++w) {
                float2 a = f2[w];
                agg[2 * w]     += a.x;
                agg[2 * w + 1] += a.y;
            }
        }
#pragma unroll
        for (int u = 0; u < 8; ++u) agg[u] *= 0.125f;

        float af[32];
#pragma unroll
        for (int w = 0; w < 4; ++w)
#pragma unroll
            for (int u = 0; u < 8; ++u)
                af[8 * w + u] = __shfl(agg[u], qb + w);

        int o0 = 8 * s;
        float h[8];
#pragma unroll
        for (int u = 0; u < 8; ++u) {
            int o = o0 + u;
            float a = 0.f;
#pragma unroll
            for (int k = 0; k < 32; ++k) a += af[k] * sw1[k * 33 + o];
            h[u] = fmaxf(a + sb1[o], 0.f);
        }

        float hf[32];
#pragma unroll
        for (int w = 0; w < 4; ++w)
#pragma unroll
            for (int u = 0; u < 8; ++u)
                hf[8 * w + u] = __shfl(h[u], qb + w);

        if (s == 0) {
            xT[34][pt] = xT[0][pt];
            xT[35][pt] = xT[1][pt];
        }
#pragma unroll
        for (int u = 0; u < 8; ++u) {
            int o = o0 + u;
            float a = 0.f;
#pragma unroll
            for (int k = 0; k < 32; ++k) a += hf[k] * sw2[k * 33 + o];
            xT[36 + o][pt] = a + sb2[o];
        }
    }
    __syncthreads();

    int pq = t & 7;
    int oq = t >> 3;

    // ---- d1: K=68, N=128 (all 256 threads) — identical to round 14 ----
    {
        float4 bb = *(const float4*)(b1 + 4 * oq);
        float4 a0 = make_float4(bb.x, bb.x, bb.x, bb.x);
        float4 a1 = make_float4(bb.y, bb.y, bb.y, bb.y);
        float4 a2 = make_float4(bb.z, bb.z, bb.z, bb.z);
        float4 a3 = make_float4(bb.w, bb.w, bb.w, bb.w);
#pragma unroll 4
        for (int k = 0; k < 68; ++k) {
            float4 xv = *(const float4*)&xT[k][4 * pq];
            float4 wv = *(const float4*)(w1 + (size_t)k * 128 + 4 * oq);
            a0.x += wv.x * xv.x; a0.y += wv.x * xv.y; a0.z += wv.x * xv.z; a0.w += wv.x * xv.w;
            a1.x += wv.y * xv.x; a1.y += wv.y * xv.y; a1.z += wv.y * xv.z; a1.w += wv.y * xv.w;
            a2.x += wv.z * xv.x; a2.y += wv.z * xv.y; a2.z += wv.z * xv.z; a2.w += wv.z * xv.w;
            a3.x += wv.w * xv.x; a3.y += wv.w * xv.y; a3.z += wv.w * xv.z; a3.w += wv.w * xv.w;
        }
        a0.x = fmaxf(a0.x, 0.f); a0.y = fmaxf(a0.y, 0.f); a0.z = fmaxf(a0.z, 0.f); a0.w = fmaxf(a0.w, 0.f);
        a1.x = fmaxf(a1.x, 0.f); a1.y = fmaxf(a1.y, 0.f); a1.z = fmaxf(a1.z, 0.f); a1.w = fmaxf(a1.w, 0.f);
        a2.x = fmaxf(a2.x, 0.f); a2.y = fmaxf(a2.y, 0.f); a2.z = fmaxf(a2.z, 0.f); a2.w = fmaxf(a2.w, 0.f);
        a3.x = fmaxf(a3.x, 0.f); a3.y = fmaxf(a3.y, 0.f); a3.z = fmaxf(a3.z, 0.f); a3.w = fmaxf(a3.w, 0.f);
        *(float4*)&h1T[4 * oq + 0][4 * pq] = a0;
        *(float4*)&h1T[4 * oq + 1][4 * pq] = a1;
        *(float4*)&h1T[4 * oq + 2][4 * pq] = a2;
        *(float4*)&h1T[4 * oq + 3][4 * pq] = a3;
    }
    __syncthreads();

    if (t < 128) {
        float4 bb = *(const float4*)(b2 + 4 * oq);
        float4 a0 = make_float4(bb.x, bb.x, bb.x, bb.x);
        float4 a1 = make_float4(bb.y, bb.y, bb.y, bb.y);
        float4 a2 = make_float4(bb.z, bb.z, bb.z, bb.z);
        float4 a3 = make_float4(bb.w, bb.w, bb.w, bb.w);
#pragma unroll 4
        for (int k = 0; k < 128; ++k) {
            float4 xv = *(const float4*)&h1T[k][4 * pq];
            float4 wv = *(const float4*)(w2 + (size_t)k * 64 + 4 * oq);
            a0.x += wv.x * xv.x; a0.y += wv.x * xv.y; a0.z += wv.x * xv.z; a0.w += wv.x * xv.w;
            a1.x += wv.y * xv.x; a1.y += wv.y * xv.y; a1.z += wv.y * xv.z; a1.w += wv.y * xv.w;
            a2.x += wv.z * xv.x; a2.y += wv.z * xv.y; a2.z += wv.z * xv.z; a2.w += wv.z * xv.w;
            a3.x += wv.w * xv.x; a3.y += wv.w * xv.y; a3.z += wv.w * xv.z; a3.w += wv.w * xv.w;
        }
        a0.x = fmaxf(a0.x, 0.f); a0.y = fmaxf(a0.y, 0.f); a0.z = fmaxf(a0.z, 0.f); a0.w = fmaxf(a0.w, 0.f);
        a1.x = fmaxf(a1.x, 0.f); a1.y = fmaxf(a1.y, 0.f); a1.z = fmaxf(a1.z, 0.f); a1.w = fmaxf(a1.w, 0.f);
        a2.x = fmaxf(a2.x, 0.f); a2.y = fmaxf(a2.y, 0.f); a2.z = fmaxf(a2.z, 0.f); a2.w = fmaxf(a2.w, 0.f);
        a3.x = fmaxf(a3.x, 0.f); a3.y = fmaxf(a3.y, 0.f); a3.z = fmaxf(a3.z, 0.f); a3.w = fmaxf(a3.w, 0.f);
        *(float4*)&h2T[4 * oq + 0][4 * pq] = a0;
        *(float4*)&h2T[4 * oq + 1][4 * pq] = a1;
        *(float4*)&h2T[4 * oq + 2][4 * pq] = a2;
        *(float4*)&h2T[4 * oq + 3][4 * pq] = a3;
    }
    __syncthreads();

    if (t < 64) {
        float4 bb = *(const float4*)(b3 + 4 * oq);
        float4 a0 = make_float4(bb.x, bb.x, bb.x, bb.x);
        float4 a1 = make_float4(bb.y, bb.y, bb.y, bb.y);
        float4 a2 = make_float4(bb.z, bb.z, bb.z, bb.z);
        float4 a3 = make_float4(bb.w, bb.w, bb.w, bb.w);
#pragma unroll 4
        for (int k = 0; k < 64; ++k) {
            float4 xv = *(const float4*)&h2T[k][4 * pq];
            float4 wv = *(const float4*)(w3 + (size_t)k * 32 + 4 * oq);
            a0.x += wv.x * xv.x; a0.y += wv.x * xv.y; a0.z += wv.x * xv.z; a0.w += wv.x * xv.w;
            a1.x += wv.y * xv.x; a1.y += wv.y * xv.y; a1.z += wv.y * xv.z; a1.w += wv.y * xv.w;
            a2.x += wv.z * xv.x; a2.y += wv.z * xv.y; a2.z += wv.z * xv.z; a2.w += wv.z * xv.w;
            a3.x += wv.w * xv.x; a3.y += wv.w * xv.y; a3.z += wv.w * xv.z; a3.w += wv.w * xv.w;
        }
        a0.x = fmaxf(a0.x, 0.f); a0.y = fmaxf(a0.y, 0.f); a0.z = fmaxf(a0.z, 0.f); a0.w = fmaxf(a0.w, 0.f);
        a1.x = fmaxf(a1.x, 0.f); a1.y = fmaxf(a1.y, 0.f); a1.z = fmaxf(a1.z, 0.f); a1.w = fmaxf(a1.w, 0.f);
        a2.x = fmaxf(a2.x, 0.f); a2.y = fmaxf(a2.y, 0.f); a2.z = fmaxf(a2.z, 0.f); a2.w = fmaxf(a2.w, 0.f);
        a3.x = fmaxf(a3.x, 0.f); a3.y = fmaxf(a3.y, 0.f); a3.z = fmaxf(a3.z, 0.f); a3.w = fmaxf(a3.w, 0.f);
        int c0 = 4 * oq;
        float s0 = g[c0 + 0] * rsqrtf(vr[c0 + 0] + EPSV);
        float s1 = g[c0 + 1] * rsqrtf(vr[c0 + 1] + EPSV);
        float s2 = g[c0 + 2] * rsqrtf(vr[c0 + 2] + EPSV);
        float s3 = g[c0 + 3] * rsqrtf(vr[c0 + 3] + EPSV);
        float w0 = s0 * ow[c0 + 0], w1c = s1 * ow[c0 + 1];
        float w2c = s2 * ow[c0 + 2], w3c = s3 * ow[c0 + 3];
        float tt = (be[c0 + 0] - mn[c0 + 0] * s0) * ow[c0 + 0]
                 + (be[c0 + 1] - mn[c0 + 1] * s1) * ow[c0 + 1]
                 + (be[c0 + 2] - mn[c0 + 2] * s2) * ow[c0 + 2]
                 + (be[c0 + 3] - mn[c0 + 3] * s3) * ow[c0 + 3];
        float4 s;
        s.x = a0.x * w0 + a1.x * w1c + a2.x * w2c + a3.x * w3c;
        s.y = a0.y * w0 + a1.y * w1c + a2.y * w2c + a3.y * w3c;
        s.z = a0.z * w0 + a1.z * w1c + a2.z * w2c + a3.z * w3c;
        s.w = a0.w * w0 + a1.w * w1c + a2.w * w2c + a3.w * w3c;
#pragma unroll
        for (int msk = 8; msk <= 32; msk <<= 1) {
            s.x += __shfl_xor(s.x, msk);
            s.y += __shfl_xor(s.y, msk);
            s.z += __shfl_xor(s.z, msk);
            s.w += __shfl_xor(s.w, msk);
            tt  += __shfl_xor(tt,  msk);
        }
        if (oq == 0) {
            float c = tt + ob[0];
            *(float4*)(out + base + 4 * pq) = make_float4(s.x + c, s.y + c, s.z + c, s.w + c);
        }
    }
}

extern "C" void kernel_launch(void* const* d_in, const int* in_sizes, int n_in,
                              void* d_out, int out_size, void* d_ws, size_t ws_size,
                              hipStream_t stream) {
    const float* inputs    = (const float*)d_in[0];
    const float* bn1_gamma = (const float*)d_in[1];
    const float* bn1_beta  = (const float*)d_in[2];
    const float* bn1_mean  = (const float*)d_in[3];
    const float* bn1_var   = (const float*)d_in[4];
    const float* g1_w1 = (const float*)d_in[5];
    const float* g1_b1 = (const float*)d_in[6];
    const float* g1_w2 = (const float*)d_in[7];
    const float* g1_b2 = (const float*)d_in[8];
    const float* g2_w1 = (const float*)d_in[9];
    const float* g2_b1 = (const float*)d_in[10];
    const float* g2_w2 = (const float*)d_in[11];
    const float* g2_b2 = (const float*)d_in[12];
    const float* d1_w = (const float*)d_in[13];
    const float* d1_b = (const float*)d_in[14];
    const float* d2_w = (const float*)d_in[15];
    const float* d2_b = (const float*)d_in[16];
    const float* d3_w = (const float*)d_in[17];
    const float* d3_b = (const float*)d_in[18];
    const float* bn2_gamma = (const float*)d_in[19];
    const float* bn2_beta  = (const float*)d_in[20];
    const float* bn2_mean  = (const float*)d_in[21];
    const float* bn2_var   = (const float*)d_in[22];
    const float* out_w = (const float*)d_in[23];
    const float* out_b = (const float*)d_in[24];
    float* out = (float*)d_out;

    const size_t BN = (size_t)BTOT * NPTS;
    char* ws = (char*)d_ws;
    size_t off = 0;
    auto alloc = [&](size_t bytes) { char* p = ws + off; off += (bytes + 255) & ~(size_t)255; return p; };
    float*  x    = (float*) alloc(BN * FTOT * sizeof(float));
    float2* pos  = (float2*)alloc(BN * sizeof(float2));
    int*    idx  = (int*)   alloc(BN * KNN  * sizeof(int));
    float*  xcat = (float*) alloc(BN * 68   * sizeof(float));   // only cols [0,34) live now
    (void)ws_size; (void)n_in; (void)in_sizes; (void)out_size;

    k_bn1<<<dim3(64),   dim3(256), 0, stream>>>(inputs, bn1_gamma, bn1_beta, bn1_mean, bn1_var, x, pos);
    k_knn<<<dim3(1024), dim3(512), 0, stream>>>(pos, idx);
    k_g1 <<<dim3(256),  dim3(256), 0, stream>>>(x, idx, g1_w1, g1_b1, g1_w2, g1_b2, xcat);
    k_g2m<<<dim3(512),  dim3(256), 0, stream>>>(xcat, idx,
                                                g2_w1, g2_b1, g2_w2, g2_b2,
                                                d1_w, d1_b, d2_w, d2_b, d3_w, d3_b,
                                                bn2_gamma, bn2_beta, bn2_mean, bn2_var,
                                                out_w, out_b, out);
}